// Round 7
// baseline (809.399 us; speedup 1.0000x reference)
//
#include <hip/hip_runtime.h>

// GNN_22505628631761: 2-layer GCN (sym-norm, self-loops) + residual + 3 outputs.
// fp32 in/out; bf16 MFMA GEMMs + bf16 h buffers internally.
// R10: GEMMs LDS-staged, counted-vmcnt 2-deep (529us proven). R11 free-run
//      regressed (FETCH/WRITE blowup) -> reverted; all gemm_x2 variants run at
//      hbm_bytes/~1.9TB/s => traffic-bound, stop tuning it.
// R12: agg1 XCD-sliced gather. h gathers (410MB random over 25.6MB) miss the
//      4MB/XCD L2 -> L3-bound. Split 128 feats into 8x16-col slices, slice =
//      blockIdx&7 pins slice to one XCD (round-robin heuristic): per-XCD
//      working set 3.2MB -> L2-resident. Requires sliced [8][N][16] layout for
//      bufA (xW1*dinv) and bufC(h1): gemm_x2 O1 epilogue writes sliced; new
//      k_gemm_h_sl reads A direct-to-reg from sliced (coalesced), B resident
//      in 32KB LDS. agg2 / gemm_h<1> keep row-major path unchanged.

typedef __attribute__((ext_vector_type(8))) short bf16x8;
typedef __attribute__((ext_vector_type(4))) float f32x4;

#define CDIV(a, b) (((a) + (b) - 1) / (b))

#define GLOBAL_AS __attribute__((address_space(1)))
#define LDS_AS __attribute__((address_space(3)))

__device__ __forceinline__ void gload16(const void* g, void* l) {
  __builtin_amdgcn_global_load_lds((const GLOBAL_AS unsigned int*)g,
                                   (LDS_AS unsigned int*)l, 16, 0, 0);
}

__device__ __forceinline__ float b2f(unsigned short u) {
  union { unsigned int i; float f; } x; x.i = ((unsigned int)u) << 16; return x.f;
}
__device__ __forceinline__ unsigned short f2b(float f) {
  union { float f; unsigned int i; } x; x.f = f;
  unsigned int r = x.i + 0x7fffu + ((x.i >> 16) & 1u);  // RNE
  return (unsigned short)(r >> 16);
}
__device__ __forceinline__ void add2(float& a0, float& a1, unsigned int u) {
  union { unsigned int i; float f; } lo, hi;
  lo.i = u << 16; hi.i = u & 0xffff0000u;
  a0 += lo.f; a1 += hi.f;
}
__device__ __forceinline__ unsigned int pack2(float lo, float hi) {
  return __builtin_amdgcn_perm(__float_as_uint(hi) + 0x8000u,
                               __float_as_uint(lo) + 0x8000u, 0x07060302u);
}

// ---------------- setup kernels ----------------

__global__ void k_wtrans4(const float* __restrict__ W1, const float* __restrict__ Wd,
                          const float* __restrict__ W2, const float* __restrict__ W3,
                          unsigned short* __restrict__ W1t, unsigned short* __restrict__ Wdt,
                          unsigned short* __restrict__ W2t, unsigned short* __restrict__ W3t) {
  int idx = blockIdx.x * blockDim.x + threadIdx.x;
  const float* in; unsigned short* out; int K, N;
  if (idx < 32768)       { in = W1; out = W1t; K = 256; N = 128; }
  else if (idx < 65536)  { in = Wd; out = Wdt; K = 256; N = 128; idx -= 32768; }
  else if (idx < 81920)  { in = W2; out = W2t; K = 128; N = 128; idx -= 65536; }
  else if (idx < 98304)  { in = W3; out = W3t; K = 128; N = 128; idx -= 81920; }
  else return;
  int k = idx / N, n = idx - k * N;
  out[n * K + k] = f2b(in[idx]);
}

// exclusive scan over deg (2048/block) + dinv = rsqrt(deg+1)
__global__ void k_scan1(const int* __restrict__ deg, int* __restrict__ lscan,
                        int* __restrict__ partials, float* __restrict__ dinv, int n) {
  __shared__ int sd[256];
  int tid = threadIdx.x;
  int base = blockIdx.x * 2048 + tid * 8;
  int v[8]; int tsum = 0;
#pragma unroll
  for (int i = 0; i < 8; ++i) {
    int idx = base + i;
    int xv = (idx < n) ? deg[idx] : 0;
    v[i] = xv; tsum += xv;
    if (idx < n) dinv[idx] = 1.0f / sqrtf((float)xv + 1.0f);
  }
  sd[tid] = tsum;
  __syncthreads();
  for (int off = 1; off < 256; off <<= 1) {
    int t = (tid >= off) ? sd[tid - off] : 0;
    __syncthreads();
    sd[tid] += t;
    __syncthreads();
  }
  int run = sd[tid] - tsum;
#pragma unroll
  for (int i = 0; i < 8; ++i) {
    int idx = base + i;
    if (idx < n) lscan[idx] = run;
    run += v[i];
  }
  if (tid == 255) partials[blockIdx.x] = sd[255];
}

__global__ void k_scan2(const int* __restrict__ partials, int* __restrict__ pprefix, int nb) {
  if (threadIdx.x == 0 && blockIdx.x == 0) {
    int run = 0;
    for (int i = 0; i < nb; ++i) { pprefix[i] = run; run += partials[i]; }
    pprefix[nb] = run;
  }
}

__global__ void k_scan3(const int* __restrict__ pprefix, int* row_start,
                        int* __restrict__ cursor, int n, int E) {
  int idx = blockIdx.x * blockDim.x + threadIdx.x;
  if (idx >= n) return;
  int v = row_start[idx] + pprefix[idx >> 11];
  row_start[idx] = v;
  cursor[idx] = v;
  if (idx == 0) row_start[n] = E;
}

// ---------------- 2-pass radix binning ----------------

#define BIN_CHUNK 4096
#define OVF_CAP 65536

__global__ __launch_bounds__(256) void k_binA(
    const int* __restrict__ ei, int E, int nbuck, int cap,
    int* __restrict__ deg, int2* __restrict__ pairs, int* __restrict__ bcnt,
    int2* __restrict__ ovf, int* __restrict__ ovf_cnt) {
  __shared__ int lcnt[256];
  __shared__ int lbase[256];
  int tid = threadIdx.x;
  for (int i = tid; i < nbuck; i += 256) lcnt[i] = 0;
  __syncthreads();
  int base_e = blockIdx.x * BIN_CHUNK;
  int src[16], dst[16], lofs[16];
#pragma unroll
  for (int i = 0; i < 16; ++i) {
    int e = base_e + i * 256 + tid;
    if (e < E) {
      int s = ei[e], d = ei[E + e];
      src[i] = s; dst[i] = d;
      atomicAdd(&deg[d], 1);
      lofs[i] = atomicAdd(&lcnt[d >> 9], 1);
    } else {
      dst[i] = -1;
    }
  }
  __syncthreads();
  for (int b = tid; b < nbuck; b += 256)
    lbase[b] = atomicAdd(&bcnt[b], lcnt[b]);
  __syncthreads();
#pragma unroll
  for (int i = 0; i < 16; ++i) {
    if (dst[i] < 0) continue;
    int b = dst[i] >> 9;
    int gpos = lbase[b] + lofs[i];
    if (gpos < cap) {
      pairs[(size_t)b * cap + gpos] = make_int2(src[i], dst[i]);
    } else {
      int op = atomicAdd(ovf_cnt, 1);
      if (op < OVF_CAP) ovf[op] = make_int2(src[i], dst[i]);
    }
  }
}

__global__ __launch_bounds__(256) void k_binB(
    const int2* __restrict__ pairs, const int* __restrict__ bcnt,
    int nbuck, int cap,
    const int2* __restrict__ ovf, const int* __restrict__ ovf_cnt,
    int* __restrict__ cursor, int* __restrict__ csr_src) {
  if ((int)blockIdx.x < nbuck) {
    int b = blockIdx.x;
    int cnt = bcnt[b]; if (cnt > cap) cnt = cap;
    const int2* p = pairs + (size_t)b * cap;
    for (int i = threadIdx.x; i < cnt; i += 256) {
      int2 e = p[i];
      int pos = atomicAdd(&cursor[e.y], 1);
      csr_src[pos] = e.x;
    }
  } else {
    int total = *ovf_cnt; if (total > OVF_CAP) total = OVF_CAP;
    int start = (blockIdx.x - nbuck) * 256 + threadIdx.x;
    for (int i = start; i < total; i += 8 * 256) {
      int2 e = ovf[i];
      int pos = atomicAdd(&cursor[e.y], 1);
      csr_src[pos] = e.x;
    }
  }
}

// ---------------- GEMMs (MFMA bf16 16x16x32) ----------------
// k_gemm_x2 / k_gemm_h: R10 LDS-staged structure (proven).
// C/D frag: col=lane&15, row=(lane>>4)*4+reg.

__global__ __launch_bounds__(512) void k_gemm_x2(
    const float* __restrict__ X,             // [n,256] fp32
    const unsigned short* __restrict__ B1t,  // [128,256] bf16 = W1^T
    const unsigned short* __restrict__ B2t,  // [128,256] bf16 = Wd^T
    const float* __restrict__ bias2,         // bd
    const float* __restrict__ dinvp,         // [n+pad] row scale for O1
    unsigned short* __restrict__ O1,         // SLICED [8][n][16] bf16
    float* __restrict__ O2, int n) {
  __shared__ char lds[65536];  // 2 x (A 16KB + B 16KB)
  const int flat = threadIdx.x;
  const int wave = flat >> 6, lane = flat & 63;
  const int l15 = lane & 15, q = lane >> 4;
  const int wM = wave >> 1, wN = wave & 1;
  const int rowBase = blockIdx.x * 128;
  const int colBase = wN * 64;

  auto stage = [&](int kb, int buf) {
    char* ldsA = lds + buf * 32768;
    char* ldsB = ldsA + 16384;
    const char* Xb = (const char*)X;
#pragma unroll
    for (int j = 0; j < 2; ++j) {
      int i = j * 512 + flat;
      int row = i >> 3, pslot = i & 7;
      int lslot = pslot ^ (row & 7);
      int rowc = rowBase + row; if (rowc >= n) rowc = n - 1;
      gload16(Xb + (size_t)rowc * 1024 + (size_t)(kb * 128 + lslot * 16),
              ldsA + (j * 512 + wave * 64) * 16);
    }
#pragma unroll
    for (int j = 0; j < 2; ++j) {
      int i = j * 512 + flat;
      int col = i >> 3, pslot = i & 7;
      int lslot = pslot ^ (col & 7);
      const char* src = (lslot >= 4) ? (const char*)B2t : (const char*)B1t;
      gload16(src + (size_t)col * 512 + kb * 64 + (lslot & 3) * 16,
              ldsB + (j * 512 + wave * 64) * 16);
    }
  };

  f32x4 acc1[2][4], acc2[2][4];
#pragma unroll
  for (int i = 0; i < 2; ++i)
#pragma unroll
    for (int j = 0; j < 4; ++j) {
      acc1[i][j] = (f32x4){0.f, 0.f, 0.f, 0.f};
      acc2[i][j] = (f32x4){0.f, 0.f, 0.f, 0.f};
    }

  stage(0, 0);
  stage(1, 1);

#pragma unroll
  for (int kb = 0; kb < 8; ++kb) {
    int cur = kb & 1;
    if (kb < 7) asm volatile("s_waitcnt vmcnt(4)" ::: "memory");
    else        asm volatile("s_waitcnt vmcnt(0)" ::: "memory");
    __builtin_amdgcn_s_barrier();
    char* ldsA = lds + cur * 32768;
    char* ldsB = ldsA + 16384;
    bf16x8 a[2], b1v[4], b2v[4];
#pragma unroll
    for (int mt = 0; mt < 2; ++mt) {
      int row = wM * 32 + mt * 16 + l15;
      uint4 lo = *(const uint4*)(ldsA + row * 128 + (((2 * q) ^ (row & 7)) * 16));
      uint4 hi = *(const uint4*)(ldsA + row * 128 + (((2 * q + 1) ^ (row & 7)) * 16));
      union { bf16x8 v; unsigned int u[4]; } r;
      r.u[0] = __builtin_amdgcn_perm(lo.y + 0x8000u, lo.x + 0x8000u, 0x07060302u);
      r.u[1] = __builtin_amdgcn_perm(lo.w + 0x8000u, lo.z + 0x8000u, 0x07060302u);
      r.u[2] = __builtin_amdgcn_perm(hi.y + 0x8000u, hi.x + 0x8000u, 0x07060302u);
      r.u[3] = __builtin_amdgcn_perm(hi.w + 0x8000u, hi.z + 0x8000u, 0x07060302u);
      a[mt] = r.v;
    }
#pragma unroll
    for (int nt = 0; nt < 4; ++nt) {
      int col = colBase + nt * 16 + l15;
      b1v[nt] = *(const bf16x8*)(ldsB + col * 128 + ((q ^ (col & 7)) * 16));
      b2v[nt] = *(const bf16x8*)(ldsB + col * 128 + (((4 + q) ^ (col & 7)) * 16));
    }
#pragma unroll
    for (int mt = 0; mt < 2; ++mt)
#pragma unroll
      for (int nt = 0; nt < 4; ++nt) {
        acc1[mt][nt] = __builtin_amdgcn_mfma_f32_16x16x32_bf16(a[mt], b1v[nt], acc1[mt][nt], 0, 0, 0);
        acc2[mt][nt] = __builtin_amdgcn_mfma_f32_16x16x32_bf16(a[mt], b2v[nt], acc2[mt][nt], 0, 0, 0);
      }
    asm volatile("s_waitcnt lgkmcnt(0)" ::: "memory");
    __builtin_amdgcn_s_barrier();
    if (kb < 6) stage(kb + 2, cur);
  }

#pragma unroll
  for (int mt = 0; mt < 2; ++mt) {
    float4 dv = *(const float4*)(dinvp + rowBase + wM * 32 + mt * 16 + q * 4);
#pragma unroll
    for (int nt = 0; nt < 4; ++nt) {
      int col = colBase + nt * 16 + l15;
      int slice = wN * 4 + nt;               // col>>4
      float bb = bias2[col];
#pragma unroll
      for (int r = 0; r < 4; ++r) {
        int row = rowBase + wM * 32 + mt * 16 + q * 4 + r;
        if (row < n) {
          float dvr = (r == 0) ? dv.x : (r == 1) ? dv.y : (r == 2) ? dv.z : dv.w;
          O1[((size_t)slice * n + row) * 16 + l15] = f2b(acc1[mt][nt][r] * dvr);
          O2[(size_t)row * 128 + col] = acc2[mt][nt][r] + bb;
        }
      }
    }
  }
}

// h1(sliced [8][n][16]) @ W2t -> Ob row-major [n,128] bf16 * dinv.
// A direct global->reg (coalesced in sliced layout); B resident in 32KB LDS.
__global__ __launch_bounds__(512) void k_gemm_h_sl(
    const unsigned short* __restrict__ X,    // sliced h1
    const unsigned short* __restrict__ Bt,   // [128,128] bf16 = W2^T
    const float* __restrict__ dinvp,
    unsigned short* __restrict__ Ob, int n) {
  __shared__ char lds[32768];
  const int flat = threadIdx.x;
  const int wave = flat >> 6, lane = flat & 63;
  const int l15 = lane & 15, q = lane >> 4;
  const int wM = wave >> 1, wN = wave & 1;
  const int rowBase = blockIdx.x * 128 + wM * 32;
  const int colBase = wN * 64;

  int rowIdx[2];
#pragma unroll
  for (int mt = 0; mt < 2; ++mt) {
    int r = rowBase + mt * 16 + l15;
    rowIdx[mt] = (r < n) ? r : (n - 1);
  }

  // A fragments direct: slice = kb*2 + (q>>1), inner = (q&1)*8 shorts
  uint4 a4[2][4];
#pragma unroll
  for (int mt = 0; mt < 2; ++mt)
#pragma unroll
    for (int kb = 0; kb < 4; ++kb) {
      size_t off = ((size_t)(kb * 2 + (q >> 1)) * n + rowIdx[mt]) * 16 + (q & 1) * 8;
      a4[mt][kb] = *(const uint4*)(X + off);
    }

  // stage B: 2048 slots of 16B, swizzled source
#pragma unroll
  for (int j = 0; j < 4; ++j) {
    int i = j * 512 + flat;
    int col = i >> 4, slot = i & 15;
    int lslot = slot ^ (col & 7);
    gload16((const char*)Bt + (size_t)col * 256 + lslot * 16,
            lds + ((size_t)j * 512 + wave * 64) * 16);
  }
  __syncthreads();

  f32x4 acc[2][4];
#pragma unroll
  for (int i = 0; i < 2; ++i)
#pragma unroll
    for (int j = 0; j < 4; ++j) acc[i][j] = (f32x4){0.f, 0.f, 0.f, 0.f};

#pragma unroll
  for (int kb = 0; kb < 4; ++kb) {
    bf16x8 b[4];
#pragma unroll
    for (int nt = 0; nt < 4; ++nt) {
      int col = colBase + nt * 16 + l15;
      int s = (kb * 4 + q) ^ (col & 7);
      b[nt] = *(const bf16x8*)(lds + (size_t)col * 256 + s * 16);
    }
#pragma unroll
    for (int mt = 0; mt < 2; ++mt) {
      bf16x8 a = *(const bf16x8*)&a4[mt][kb];
#pragma unroll
      for (int nt = 0; nt < 4; ++nt)
        acc[mt][nt] = __builtin_amdgcn_mfma_f32_16x16x32_bf16(a, b[nt], acc[mt][nt], 0, 0, 0);
    }
  }

#pragma unroll
  for (int mt = 0; mt < 2; ++mt) {
    float4 dv = *(const float4*)(dinvp + rowBase + mt * 16 + q * 4);
#pragma unroll
    for (int nt = 0; nt < 4; ++nt) {
      int col = colBase + nt * 16 + l15;
#pragma unroll
      for (int r = 0; r < 4; ++r) {
        int row = rowBase + mt * 16 + q * 4 + r;
        if (row < n) {
          float dvr = (r == 0) ? dv.x : (r == 1) ? dv.y : (r == 2) ? dv.z : dv.w;
          Ob[(size_t)row * 128 + col] = f2b(acc[mt][nt][r] * dvr);
        }
      }
    }
  }
}

// A bf16 [n,128] row-major @ Bt + bias -> fp32 (R10 structure, OUT_F32 path)
__global__ __launch_bounds__(512) void k_gemm_h_f32(
    const unsigned short* __restrict__ X, const unsigned short* __restrict__ Bt,
    const float* __restrict__ bias, float* __restrict__ Of, int n) {
  __shared__ char lds[65536];
  const int flat = threadIdx.x;
  const int wave = flat >> 6, lane = flat & 63;
  const int l15 = lane & 15, q = lane >> 4;
  const int wM = wave >> 1, wN = wave & 1;
  const int rowBase = blockIdx.x * 128;
  const int colBase = wN * 64;

  auto stage = [&](int ks, int buf) {
    char* ldsA = lds + buf * 32768;
    char* ldsB = ldsA + 16384;
#pragma unroll
    for (int j = 0; j < 2; ++j) {
      int i = j * 512 + flat;
      int row = i >> 3, pslot = i & 7;
      int lslot = pslot ^ (row & 7);
      int rowc = rowBase + row; if (rowc >= n) rowc = n - 1;
      gload16((const char*)X + (size_t)rowc * 256 + ks * 128 + lslot * 16,
              ldsA + (j * 512 + wave * 64) * 16);
    }
#pragma unroll
    for (int j = 0; j < 2; ++j) {
      int i = j * 512 + flat;
      int col = i >> 3, pslot = i & 7;
      int lslot = pslot ^ (col & 7);
      gload16((const char*)Bt + (size_t)col * 256 + ks * 128 + lslot * 16,
              ldsB + (j * 512 + wave * 64) * 16);
    }
  };

  f32x4 acc[2][4];
#pragma unroll
  for (int i = 0; i < 2; ++i)
#pragma unroll
    for (int j = 0; j < 4; ++j) acc[i][j] = (f32x4){0.f, 0.f, 0.f, 0.f};

  stage(0, 0);
  stage(1, 1);

#pragma unroll
  for (int ks = 0; ks < 2; ++ks) {
    if (ks == 0) asm volatile("s_waitcnt vmcnt(4)" ::: "memory");
    else         asm volatile("s_waitcnt vmcnt(0)" ::: "memory");
    __builtin_amdgcn_s_barrier();
    char* ldsA = lds + ks * 32768;
    char* ldsB = ldsA + 16384;
#pragma unroll
    for (int k2 = 0; k2 < 2; ++k2) {
      bf16x8 a[2], b[4];
#pragma unroll
      for (int mt = 0; mt < 2; ++mt) {
        int row = wM * 32 + mt * 16 + l15;
        a[mt] = *(const bf16x8*)(ldsA + row * 128 + (((k2 * 4 + q) ^ (row & 7)) * 16));
      }
#pragma unroll
      for (int nt = 0; nt < 4; ++nt) {
        int col = colBase + nt * 16 + l15;
        b[nt] = *(const bf16x8*)(ldsB + col * 128 + (((k2 * 4 + q) ^ (col & 7)) * 16));
      }
#pragma unroll
      for (int mt = 0; mt < 2; ++mt)
#pragma unroll
        for (int nt = 0; nt < 4; ++nt)
          acc[mt][nt] = __builtin_amdgcn_mfma_f32_16x16x32_bf16(a[mt], b[nt], acc[mt][nt], 0, 0, 0);
    }
  }

#pragma unroll
  for (int mt = 0; mt < 2; ++mt)
#pragma unroll
    for (int nt = 0; nt < 4; ++nt) {
      int col = colBase + nt * 16 + l15;
      float bb = bias[col];
#pragma unroll
      for (int r = 0; r < 4; ++r) {
        int row = rowBase + wM * 32 + mt * 16 + q * 4 + r;
        if (row < n)
          __builtin_nontemporal_store(acc[mt][nt][r] + bb, &Of[(size_t)row * 128 + col]);
      }
    }
}

// ---------------- aggregation ----------------
// agg1: XCD-sliced. slice = blockIdx&7 (-> one XCD via round-robin dispatch);
// per slice, gather 16 cols/node: 2 lanes per edge (32B), 32 edges/load-instr.
// h (bufA) and output (bufC h1) in sliced [8][N][16] layout.

__global__ __launch_bounds__(256) void k_agg1_sl(
    const unsigned short* __restrict__ hA,   // sliced xW1*dinv
    const int* __restrict__ row_start, const int* __restrict__ csr_src,
    const float* __restrict__ dinv,
    const float* __restrict__ bias,          // b1
    unsigned short* __restrict__ hout,       // sliced h1
    int n) {
  int s = blockIdx.x & 7;
  int gw = (blockIdx.x >> 3) * 4 + (threadIdx.x >> 6);
  int lane = threadIdx.x & 63;
  int sub2 = lane & 1;
  if (gw >= n) return;
  int beg = row_start[gw], end = row_start[gw + 1];
  const unsigned short* hs = hA + (size_t)s * n * 16;
  float acc[8] = {0.f, 0.f, 0.f, 0.f, 0.f, 0.f, 0.f, 0.f};
  for (int base = beg; base < end; base += 64) {
    int idx_l = (base + lane < end) ? csr_src[base + lane] : 0;
#pragma unroll
    for (int j = 0; j < 64; j += 32) {
      if (base + j >= end) break;
      int e = j + (lane >> 1);
      int se = __builtin_amdgcn_ds_bpermute(e << 2, idx_l);
      uint4 v = *(const uint4*)(hs + (size_t)se * 16 + sub2 * 8);
      if (base + e < end) {
        add2(acc[0], acc[1], v.x); add2(acc[2], acc[3], v.y);
        add2(acc[4], acc[5], v.z); add2(acc[6], acc[7], v.w);
      }
    }
  }
#pragma unroll
  for (int i = 0; i < 8; ++i) {
    acc[i] += __shfl_xor(acc[i], 2);
    acc[i] += __shfl_xor(acc[i], 4);
    acc[i] += __shfl_xor(acc[i], 8);
    acc[i] += __shfl_xor(acc[i], 16);
    acc[i] += __shfl_xor(acc[i], 32);
  }
  if (lane < 2) {
    float dg = dinv[gw];
    uint4 sv = *(const uint4*)(hs + (size_t)gw * 16 + sub2 * 8);  // self (pre-scaled)
    add2(acc[0], acc[1], sv.x); add2(acc[2], acc[3], sv.y);
    add2(acc[4], acc[5], sv.z); add2(acc[6], acc[7], sv.w);
    const float* bp = bias + s * 16 + sub2 * 8;
    float4 b0 = *(const float4*)bp;
    float4 b1v = *(const float4*)(bp + 4);
    float a[8];
    a[0] = fmaxf(acc[0] * dg + b0.x, 0.f); a[1] = fmaxf(acc[1] * dg + b0.y, 0.f);
    a[2] = fmaxf(acc[2] * dg + b0.z, 0.f); a[3] = fmaxf(acc[3] * dg + b0.w, 0.f);
    a[4] = fmaxf(acc[4] * dg + b1v.x, 0.f); a[5] = fmaxf(acc[5] * dg + b1v.y, 0.f);
    a[6] = fmaxf(acc[6] * dg + b1v.z, 0.f); a[7] = fmaxf(acc[7] * dg + b1v.w, 0.f);
    uint4 o;
    o.x = pack2(a[0], a[1]); o.y = pack2(a[2], a[3]);
    o.z = pack2(a[4], a[5]); o.w = pack2(a[6], a[7]);
    *(uint4*)(hout + ((size_t)s * n + gw) * 16 + sub2 * 8) = o;
  }
}

// agg2 (row-major gather, fused epilogue) — unchanged R8 structure.
__device__ __forceinline__ void agg_edges4(
    const unsigned short* __restrict__ h, const int* __restrict__ csr_src,
    int beg, int end, int lane, int grp, int sub, float* acc) {
  for (int base = beg; base < end; base += 64) {
    int m = end - base; if (m > 64) m = 64;
    int idx_l = (base + lane < end) ? csr_src[base + lane] : 0;
    for (int j = 0; j < m; j += 16) {
      int s0 = __builtin_amdgcn_ds_bpermute((j + grp) << 2, idx_l);
      int s1 = __builtin_amdgcn_ds_bpermute((j + 4 + grp) << 2, idx_l);
      int s2 = __builtin_amdgcn_ds_bpermute((j + 8 + grp) << 2, idx_l);
      int s3 = __builtin_amdgcn_ds_bpermute((j + 12 + grp) << 2, idx_l);
      uint4 v0 = *(const uint4*)(h + (size_t)s0 * 128 + sub * 8);
      uint4 v1 = *(const uint4*)(h + (size_t)s1 * 128 + sub * 8);
      uint4 v2 = *(const uint4*)(h + (size_t)s2 * 128 + sub * 8);
      uint4 v3 = *(const uint4*)(h + (size_t)s3 * 128 + sub * 8);
      if (j + grp < m) {
        add2(acc[0], acc[1], v0.x); add2(acc[2], acc[3], v0.y);
        add2(acc[4], acc[5], v0.z); add2(acc[6], acc[7], v0.w);
      }
      if (j + 4 + grp < m) {
        add2(acc[0], acc[1], v1.x); add2(acc[2], acc[3], v1.y);
        add2(acc[4], acc[5], v1.z); add2(acc[6], acc[7], v1.w);
      }
      if (j + 8 + grp < m) {
        add2(acc[0], acc[1], v2.x); add2(acc[2], acc[3], v2.y);
        add2(acc[4], acc[5], v2.z); add2(acc[6], acc[7], v2.w);
      }
      if (j + 12 + grp < m) {
        add2(acc[0], acc[1], v3.x); add2(acc[2], acc[3], v3.y);
        add2(acc[4], acc[5], v3.z); add2(acc[6], acc[7], v3.w);
      }
    }
  }
}

__global__ __launch_bounds__(256) void k_agg2_epi(
    const unsigned short* __restrict__ h,   // dinv-scaled h1@W2 bf16 [n,128]
    const int* __restrict__ row_start, const int* __restrict__ csr_src,
    const float* __restrict__ dinv,
    const float* __restrict__ bias,    // b2
    float* res_out1,                   // in: x@Wd+bd; out: log_softmax
    const float* __restrict__ wdeg, const float* __restrict__ bdeg,
    float* __restrict__ out2,          // [n]
    unsigned short* __restrict__ hf,   // h bf16 [n,128]
    int n) {
  int gw = blockIdx.x * 4 + (threadIdx.x >> 6);
  int lane = threadIdx.x & 63;
  int grp = lane >> 4, sub = lane & 15;
  if (gw >= n) return;
  int beg = row_start[gw], end = row_start[gw + 1];
  float acc[8] = {0.f, 0.f, 0.f, 0.f, 0.f, 0.f, 0.f, 0.f};
  agg_edges4(h, csr_src, beg, end, lane, grp, sub, acc);
#pragma unroll
  for (int i = 0; i < 8; ++i) {
    acc[i] += __shfl_xor(acc[i], 16);
    acc[i] += __shfl_xor(acc[i], 32);
  }
  if (grp == 0) {
    float dg = dinv[gw];
    uint4 sv = *(const uint4*)(h + (size_t)gw * 128 + sub * 8);
    add2(acc[0], acc[1], sv.x); add2(acc[2], acc[3], sv.y);
    add2(acc[4], acc[5], sv.z); add2(acc[6], acc[7], sv.w);
    float4 b0 = *(const float4*)(bias + sub * 8);
    float4 b1v = *(const float4*)(bias + sub * 8 + 4);
    float4 r0 = *(const float4*)(res_out1 + (size_t)gw * 128 + sub * 8);
    float4 r1 = *(const float4*)(res_out1 + (size_t)gw * 128 + sub * 8 + 4);
    float a[8];
    a[0] = acc[0] * dg + b0.x + r0.x; a[1] = acc[1] * dg + b0.y + r0.y;
    a[2] = acc[2] * dg + b0.z + r0.z; a[3] = acc[3] * dg + b0.w + r0.w;
    a[4] = acc[4] * dg + b1v.x + r1.x; a[5] = acc[5] * dg + b1v.y + r1.y;
    a[6] = acc[6] * dg + b1v.z + r1.z; a[7] = acc[7] * dg + b1v.w + r1.w;
    uint4 o;
    o.x = pack2(a[0], a[1]); o.y = pack2(a[2], a[3]);
    o.z = pack2(a[4], a[5]); o.w = pack2(a[6], a[7]);
    *(uint4*)(hf + (size_t)gw * 128 + sub * 8) = o;
    // result2 (degree head)
    float4 w0 = *(const float4*)(wdeg + sub * 8);
    float4 w1 = *(const float4*)(wdeg + sub * 8 + 4);
    float t = a[0] * w0.x + a[1] * w0.y + a[2] * w0.z + a[3] * w0.w +
              a[4] * w1.x + a[5] * w1.y + a[6] * w1.z + a[7] * w1.w;
#pragma unroll
    for (int mk = 8; mk >= 1; mk >>= 1) t += __shfl_xor(t, mk);
    if (sub == 0) __builtin_nontemporal_store(t + bdeg[0], out2 + gw);
    // log_softmax
    float mx = a[0];
#pragma unroll
    for (int i = 1; i < 8; ++i) mx = fmaxf(mx, a[i]);
#pragma unroll
    for (int mk = 8; mk >= 1; mk >>= 1) mx = fmaxf(mx, __shfl_xor(mx, mk));
    float l = 0.f;
#pragma unroll
    for (int i = 0; i < 8; ++i) l += __expf(a[i] - mx);
#pragma unroll
    for (int mk = 8; mk >= 1; mk >>= 1) l += __shfl_xor(l, mk);
    float ls = mx + __logf(l);
    f32x4 o0 = {a[0] - ls, a[1] - ls, a[2] - ls, a[3] - ls};
    f32x4 o1 = {a[4] - ls, a[5] - ls, a[6] - ls, a[7] - ls};
    __builtin_nontemporal_store(o0, (f32x4*)(res_out1 + (size_t)gw * 128 + sub * 8));
    __builtin_nontemporal_store(o1, (f32x4*)(res_out1 + (size_t)gw * 128 + sub * 8 + 4));
  }
}

// ---------------- launch ----------------

extern "C" void kernel_launch(void* const* d_in, const int* in_sizes, int n_in,
                              void* d_out, int out_size, void* d_ws, size_t ws_size,
                              hipStream_t stream) {
  const float* x   = (const float*)d_in[0];
  const int*   ei  = (const int*)d_in[1];
  const float* W1  = (const float*)d_in[2];
  const float* b1  = (const float*)d_in[3];
  const float* W2  = (const float*)d_in[4];
  const float* b2  = (const float*)d_in[5];
  const float* Wd  = (const float*)d_in[6];
  const float* bd  = (const float*)d_in[7];
  const float* Wdg = (const float*)d_in[8];
  const float* bdg = (const float*)d_in[9];
  const float* W3  = (const float*)d_in[10];
  const float* b3  = (const float*)d_in[11];

  const int N = in_sizes[0] / 256;
  const int E = in_sizes[1] / 2;

  // ---- workspace (~35 MB) ----
  char* w = (char*)d_ws;
  auto alloc = [&](size_t bytes) {
    char* p = w;
    w += (bytes + 255) & ~(size_t)255;
    return p;
  };
  unsigned short* W1t  = (unsigned short*)alloc((size_t)256 * 128 * 2);
  unsigned short* Wdt  = (unsigned short*)alloc((size_t)256 * 128 * 2);
  unsigned short* W2t  = (unsigned short*)alloc((size_t)128 * 128 * 2);
  unsigned short* W3t  = (unsigned short*)alloc((size_t)128 * 128 * 2);
  unsigned short* bufC = (unsigned short*)alloc((size_t)N * 128 * 2);  // pairs scratch -> h1(sliced) -> h
  int*   deg      = (int*)alloc((size_t)N * 4);
  float* dinv     = (float*)alloc((size_t)(N + 128) * 4);
  int*   row_start= (int*)alloc((size_t)(N + 1) * 4);
  int*   cursor   = (int*)alloc((size_t)N * 4);
  int*   partials = (int*)alloc(4096);
  int*   pprefix  = (int*)alloc(4096);
  int*   csr_src  = (int*)alloc((size_t)E * 4);
  int*   bcnt     = (int*)alloc(2048);
  int*   ovf_cnt  = bcnt + 256;
  int2*  ovf      = (int2*)alloc((size_t)OVF_CAP * 8);

  // ---- d_out regions; out3 doubles as bf16 scratch bufA ----
  float* out1 = (float*)d_out;               // residual, then log_softmax
  float* out2 = out1 + (size_t)N * 128;
  float* out3 = out2 + (size_t)N;
  unsigned short* bufA = (unsigned short*)out3;  // xW1*dinv (sliced) / h1W2 (row-major)

  const int nbuck = CDIV(N, 512);
  int cap = (E / nbuck) + (E / nbuck) / 2;
  cap = (cap + 255) & ~255;
  size_t bufC_bytes = (size_t)N * 128 * 2;
  if ((size_t)nbuck * cap * 8 > bufC_bytes)
    cap = (int)(bufC_bytes / ((size_t)nbuck * 8));
  int2* pairs = (int2*)bufC;

  hipMemsetAsync(deg, 0, (size_t)N * 4, stream);
  hipMemsetAsync(bcnt, 0, 2048, stream);

  k_wtrans4<<<CDIV(98304, 256), 256, 0, stream>>>(W1, Wd, W2, W3, W1t, Wdt, W2t, W3t);

  // deg count + pair binning (one ei pass)
  k_binA<<<CDIV(E, BIN_CHUNK), 256, 0, stream>>>(ei, E, nbuck, cap, deg, pairs,
                                                 bcnt, ovf, ovf_cnt);

  // dinv before gemm_x2 (O1 rows scaled by dinv)
  const int nb = CDIV(N, 2048);
  k_scan1<<<nb, 256, 0, stream>>>(deg, row_start, partials, dinv, N);
  k_scan2<<<1, 64, 0, stream>>>(partials, pprefix, nb);
  k_scan3<<<CDIV(N, 256), 256, 0, stream>>>(pprefix, row_start, cursor, N, E);

  // fused x@W1*dinv -> bufA (SLICED bf16), x@Wd+bd -> out1 (fp32 residual)
  k_gemm_x2<<<CDIV(N, 128), 512, 0, stream>>>(x, W1t, Wdt, bd, dinv, bufA, out1, N);

  // bucket-local scatter -> csr_src
  k_binB<<<nbuck + 8, 256, 0, stream>>>(pairs, bcnt, nbuck, cap, ovf, ovf_cnt,
                                        cursor, csr_src);

  // layer 1: XCD-sliced aggregate -> h1 (bufC, sliced)
  k_agg1_sl<<<8 * CDIV(N, 4), 256, 0, stream>>>(bufA, row_start, csr_src, dinv,
                                                b1, bufC, N);

  // h1(sliced) @ W2 * dinv -> bufA (row-major bf16)
  k_gemm_h_sl<<<CDIV(N, 128), 512, 0, stream>>>(bufC, W2t, dinv, bufA, N);

  // layer 2 aggregate + b2 + residual; log_softmax -> out1, deg head -> out2,
  // h bf16 -> bufC (row-major)
  k_agg2_epi<<<CDIV(N, 4), 256, 0, stream>>>(bufA, row_start, csr_src, dinv,
                                             b2, out1, Wdg, bdg, out2, bufC, N);

  // result3 = h @ W3 + b3 -> out3
  k_gemm_h_f32<<<CDIV(N, 128), 512, 0, stream>>>(bufC, W3t, b3, out3, N);
}

// Round 8
// 500.232 us; speedup vs baseline: 1.6180x; 1.6180x over previous
//
#include <hip/hip_runtime.h>

// GNN_22505628631761: 2-layer GCN (sym-norm, self-loops) + residual + 3 outputs.
// fp32 in/out; bf16 MFMA GEMMs + bf16 h buffers internally.
// R10: GEMMs LDS-staged + counted vmcnt; aggs 4-edges/instr (529us proven).
// R12 post-mortem: XCD-sliced agg1 made gathers L2-resident (FETCH 225->43MB,
//      cache mechanism confirmed) but 8x edge-machinery => VALU-bound 361us.
//      Reverted to row-major aggs.
// R13: (a) binB LDS-cursor: each block owns one 512-node bucket -> cursor
//      slice private; 1.6M global atomics -> LDS atomics on 2KB counter
//      array (guarded by ovf_cnt==0 for spill coherence).
//      (b) deg/bcnt zeroing folded into k_wtrans4 tail (-2 dispatches).

typedef __attribute__((ext_vector_type(8))) short bf16x8;
typedef __attribute__((ext_vector_type(4))) float f32x4;

#define CDIV(a, b) (((a) + (b) - 1) / (b))

#define GLOBAL_AS __attribute__((address_space(1)))
#define LDS_AS __attribute__((address_space(3)))

__device__ __forceinline__ void gload16(const void* g, void* l) {
  __builtin_amdgcn_global_load_lds((const GLOBAL_AS unsigned int*)g,
                                   (LDS_AS unsigned int*)l, 16, 0, 0);
}

__device__ __forceinline__ float b2f(unsigned short u) {
  union { unsigned int i; float f; } x; x.i = ((unsigned int)u) << 16; return x.f;
}
__device__ __forceinline__ unsigned short f2b(float f) {
  union { float f; unsigned int i; } x; x.f = f;
  unsigned int r = x.i + 0x7fffu + ((x.i >> 16) & 1u);  // RNE
  return (unsigned short)(r >> 16);
}
// add both bf16 halves of u into a0 (low) / a1 (high)
__device__ __forceinline__ void add2(float& a0, float& a1, unsigned int u) {
  union { unsigned int i; float f; } lo, hi;
  lo.i = u << 16; hi.i = u & 0xffff0000u;
  a0 += lo.f; a1 += hi.f;
}
__device__ __forceinline__ unsigned int pack2(float lo, float hi) {
  return __builtin_amdgcn_perm(__float_as_uint(hi) + 0x8000u,
                               __float_as_uint(lo) + 0x8000u, 0x07060302u);
}

// ---------------- setup kernels ----------------

// all four W [K][N] fp32 -> Wt [N][K] bf16, plus deg/bcnt zero-init tail
__global__ void k_wtrans4(const float* __restrict__ W1, const float* __restrict__ Wd,
                          const float* __restrict__ W2, const float* __restrict__ W3,
                          unsigned short* __restrict__ W1t, unsigned short* __restrict__ Wdt,
                          unsigned short* __restrict__ W2t, unsigned short* __restrict__ W3t,
                          int* __restrict__ deg, int* __restrict__ bcnt, int n) {
  int idx = blockIdx.x * blockDim.x + threadIdx.x;
  if (idx >= 98304) {
    idx -= 98304;
    if (idx < n) deg[idx] = 0;
    else if (idx - n < 512) bcnt[idx - n] = 0;
    return;
  }
  const float* in; unsigned short* out; int K, N;
  if (idx < 32768)       { in = W1; out = W1t; K = 256; N = 128; }
  else if (idx < 65536)  { in = Wd; out = Wdt; K = 256; N = 128; idx -= 32768; }
  else if (idx < 81920)  { in = W2; out = W2t; K = 128; N = 128; idx -= 65536; }
  else                   { in = W3; out = W3t; K = 128; N = 128; idx -= 81920; }
  int k = idx / N, nn = idx - k * N;
  out[nn * K + k] = f2b(in[idx]);
}

// exclusive scan over deg (2048/block) + dinv = rsqrt(deg+1)
__global__ void k_scan1(const int* __restrict__ deg, int* __restrict__ lscan,
                        int* __restrict__ partials, float* __restrict__ dinv, int n) {
  __shared__ int sd[256];
  int tid = threadIdx.x;
  int base = blockIdx.x * 2048 + tid * 8;
  int v[8]; int tsum = 0;
#pragma unroll
  for (int i = 0; i < 8; ++i) {
    int idx = base + i;
    int xv = (idx < n) ? deg[idx] : 0;
    v[i] = xv; tsum += xv;
    if (idx < n) dinv[idx] = 1.0f / sqrtf((float)xv + 1.0f);
  }
  sd[tid] = tsum;
  __syncthreads();
  for (int off = 1; off < 256; off <<= 1) {
    int t = (tid >= off) ? sd[tid - off] : 0;
    __syncthreads();
    sd[tid] += t;
    __syncthreads();
  }
  int run = sd[tid] - tsum;
#pragma unroll
  for (int i = 0; i < 8; ++i) {
    int idx = base + i;
    if (idx < n) lscan[idx] = run;
    run += v[i];
  }
  if (tid == 255) partials[blockIdx.x] = sd[255];
}

__global__ void k_scan2(const int* __restrict__ partials, int* __restrict__ pprefix, int nb) {
  if (threadIdx.x == 0 && blockIdx.x == 0) {
    int run = 0;
    for (int i = 0; i < nb; ++i) { pprefix[i] = run; run += partials[i]; }
    pprefix[nb] = run;
  }
}

__global__ void k_scan3(const int* __restrict__ pprefix, int* row_start,
                        int* __restrict__ cursor, int n, int E) {
  int idx = blockIdx.x * blockDim.x + threadIdx.x;
  if (idx >= n) return;
  int v = row_start[idx] + pprefix[idx >> 11];
  row_start[idx] = v;
  cursor[idx] = v;
  if (idx == 0) row_start[n] = E;
}

// ---------------- 2-pass radix binning ----------------

#define BIN_CHUNK 4096  // edges per block in pass A (16/thread)
#define OVF_CAP 65536

__global__ __launch_bounds__(256) void k_binA(
    const int* __restrict__ ei, int E, int nbuck, int cap,
    int* __restrict__ deg, int2* __restrict__ pairs, int* __restrict__ bcnt,
    int2* __restrict__ ovf, int* __restrict__ ovf_cnt) {
  __shared__ int lcnt[256];
  __shared__ int lbase[256];
  int tid = threadIdx.x;
  for (int i = tid; i < nbuck; i += 256) lcnt[i] = 0;
  __syncthreads();
  int base_e = blockIdx.x * BIN_CHUNK;
  int src[16], dst[16], lofs[16];
#pragma unroll
  for (int i = 0; i < 16; ++i) {
    int e = base_e + i * 256 + tid;
    if (e < E) {
      int s = ei[e], d = ei[E + e];
      src[i] = s; dst[i] = d;
      atomicAdd(&deg[d], 1);
      lofs[i] = atomicAdd(&lcnt[d >> 9], 1);
    } else {
      dst[i] = -1;
    }
  }
  __syncthreads();
  for (int b = tid; b < nbuck; b += 256)
    lbase[b] = atomicAdd(&bcnt[b], lcnt[b]);
  __syncthreads();
#pragma unroll
  for (int i = 0; i < 16; ++i) {
    if (dst[i] < 0) continue;
    int b = dst[i] >> 9;
    int gpos = lbase[b] + lofs[i];
    if (gpos < cap) {
      pairs[(size_t)b * cap + gpos] = make_int2(src[i], dst[i]);
    } else {
      int op = atomicAdd(ovf_cnt, 1);
      if (op < OVF_CAP) ovf[op] = make_int2(src[i], dst[i]);
    }
  }
}

__global__ __launch_bounds__(256) void k_binB(
    const int2* __restrict__ pairs, const int* __restrict__ bcnt,
    int nbuck, int cap,
    const int2* __restrict__ ovf, const int* __restrict__ ovf_cnt,
    int* __restrict__ cursor, int* __restrict__ csr_src, int n) {
  int ov = *ovf_cnt;
  if ((int)blockIdx.x < nbuck) {
    int b = blockIdx.x;
    int cnt = bcnt[b]; if (cnt > cap) cnt = cap;
    const int2* p = pairs + (size_t)b * cap;
    if (ov == 0) {
      // bucket-private cursors in LDS (bucket = 512 nodes)
      __shared__ int lcur[512];
      int nbase = b << 9;
      for (int i = threadIdx.x; i < 512; i += 256) {
        int node = nbase + i;
        lcur[i] = (node < n) ? cursor[node] : 0;
      }
      __syncthreads();
      for (int i = threadIdx.x; i < cnt; i += 256) {
        int2 e = p[i];
        int pos = atomicAdd(&lcur[e.y - nbase], 1);
        csr_src[pos] = e.x;
      }
    } else {
      for (int i = threadIdx.x; i < cnt; i += 256) {
        int2 e = p[i];
        int pos = atomicAdd(&cursor[e.y], 1);
        csr_src[pos] = e.x;
      }
    }
  } else {
    int total = ov; if (total > OVF_CAP) total = OVF_CAP;
    int start = (blockIdx.x - nbuck) * 256 + threadIdx.x;
    for (int i = start; i < total; i += 8 * 256) {
      int2 e = ovf[i];
      int pos = atomicAdd(&cursor[e.y], 1);
      csr_src[pos] = e.x;
    }
  }
}

// ---------------- GEMMs (MFMA bf16 16x16x32, LDS-staged) ----------------
// Block 128 rows x 128 cols, 512 thr (8 waves, 4x2), wave tile 32x64 (2x4).
// LDS dest linear (global_load_lds), source pre-swizzled slot^=(row&7).
// C/D: col=lane&15, row=(lane>>4)*4+reg.

__global__ __launch_bounds__(512) void k_gemm_x2(
    const float* __restrict__ X,             // [n,256] fp32
    const unsigned short* __restrict__ B1t,  // [128,256] bf16 = W1^T
    const unsigned short* __restrict__ B2t,  // [128,256] bf16 = Wd^T
    const float* __restrict__ bias2,         // bd
    const float* __restrict__ dinvp,         // [n+pad] row scale for O1
    unsigned short* __restrict__ O1, float* __restrict__ O2, int n) {
  __shared__ char lds[65536];  // 2 x (A 16KB + B 16KB)
  const int flat = threadIdx.x;
  const int wave = flat >> 6, lane = flat & 63;
  const int l15 = lane & 15, q = lane >> 4;
  const int wM = wave >> 1, wN = wave & 1;
  const int rowBase = blockIdx.x * 128;
  const int colBase = wN * 64;

  auto stage = [&](int kb, int buf) {
    char* ldsA = lds + buf * 32768;
    char* ldsB = ldsA + 16384;
    const char* Xb = (const char*)X;
#pragma unroll
    for (int j = 0; j < 2; ++j) {
      int i = j * 512 + flat;
      int row = i >> 3, pslot = i & 7;
      int lslot = pslot ^ (row & 7);
      int rowc = rowBase + row; if (rowc >= n) rowc = n - 1;
      gload16(Xb + (size_t)rowc * 1024 + (size_t)(kb * 128 + lslot * 16),
              ldsA + (j * 512 + wave * 64) * 16);
    }
#pragma unroll
    for (int j = 0; j < 2; ++j) {
      int i = j * 512 + flat;
      int col = i >> 3, pslot = i & 7;
      int lslot = pslot ^ (col & 7);
      const char* src = (lslot >= 4) ? (const char*)B2t : (const char*)B1t;
      gload16(src + (size_t)col * 512 + kb * 64 + (lslot & 3) * 16,
              ldsB + (j * 512 + wave * 64) * 16);
    }
  };

  f32x4 acc1[2][4], acc2[2][4];
#pragma unroll
  for (int i = 0; i < 2; ++i)
#pragma unroll
    for (int j = 0; j < 4; ++j) {
      acc1[i][j] = (f32x4){0.f, 0.f, 0.f, 0.f};
      acc2[i][j] = (f32x4){0.f, 0.f, 0.f, 0.f};
    }

  stage(0, 0);
  stage(1, 1);

#pragma unroll
  for (int kb = 0; kb < 8; ++kb) {
    int cur = kb & 1;
    if (kb < 7) asm volatile("s_waitcnt vmcnt(4)" ::: "memory");
    else        asm volatile("s_waitcnt vmcnt(0)" ::: "memory");
    __builtin_amdgcn_s_barrier();
    char* ldsA = lds + cur * 32768;
    char* ldsB = ldsA + 16384;
    bf16x8 a[2], b1v[4], b2v[4];
#pragma unroll
    for (int mt = 0; mt < 2; ++mt) {
      int row = wM * 32 + mt * 16 + l15;
      uint4 lo = *(const uint4*)(ldsA + row * 128 + (((2 * q) ^ (row & 7)) * 16));
      uint4 hi = *(const uint4*)(ldsA + row * 128 + (((2 * q + 1) ^ (row & 7)) * 16));
      union { bf16x8 v; unsigned int u[4]; } r;
      r.u[0] = __builtin_amdgcn_perm(lo.y + 0x8000u, lo.x + 0x8000u, 0x07060302u);
      r.u[1] = __builtin_amdgcn_perm(lo.w + 0x8000u, lo.z + 0x8000u, 0x07060302u);
      r.u[2] = __builtin_amdgcn_perm(hi.y + 0x8000u, hi.x + 0x8000u, 0x07060302u);
      r.u[3] = __builtin_amdgcn_perm(hi.w + 0x8000u, hi.z + 0x8000u, 0x07060302u);
      a[mt] = r.v;
    }
#pragma unroll
    for (int nt = 0; nt < 4; ++nt) {
      int col = colBase + nt * 16 + l15;
      b1v[nt] = *(const bf16x8*)(ldsB + col * 128 + ((q ^ (col & 7)) * 16));
      b2v[nt] = *(const bf16x8*)(ldsB + col * 128 + (((4 + q) ^ (col & 7)) * 16));
    }
#pragma unroll
    for (int mt = 0; mt < 2; ++mt)
#pragma unroll
      for (int nt = 0; nt < 4; ++nt) {
        acc1[mt][nt] = __builtin_amdgcn_mfma_f32_16x16x32_bf16(a[mt], b1v[nt], acc1[mt][nt], 0, 0, 0);
        acc2[mt][nt] = __builtin_amdgcn_mfma_f32_16x16x32_bf16(a[mt], b2v[nt], acc2[mt][nt], 0, 0, 0);
      }
    asm volatile("s_waitcnt lgkmcnt(0)" ::: "memory");
    __builtin_amdgcn_s_barrier();
    if (kb < 6) stage(kb + 2, cur);
  }

#pragma unroll
  for (int mt = 0; mt < 2; ++mt) {
    float4 dv = *(const float4*)(dinvp + rowBase + wM * 32 + mt * 16 + q * 4);
#pragma unroll
    for (int nt = 0; nt < 4; ++nt) {
      int col = colBase + nt * 16 + l15;
      float bb = bias2[col];
#pragma unroll
      for (int r = 0; r < 4; ++r) {
        int row = rowBase + wM * 32 + mt * 16 + q * 4 + r;
        if (row < n) {
          float dvr = (r == 0) ? dv.x : (r == 1) ? dv.y : (r == 2) ? dv.z : dv.w;
          O1[(size_t)row * 128 + col] = f2b(acc1[mt][nt][r] * dvr);
          O2[(size_t)row * 128 + col] = acc2[mt][nt][r] + bb;
        }
      }
    }
  }
}

// A bf16 [n,128] @ Bt bf16 [128,128] -> bf16*dinv (OUT_F32=0) or fp32+bias (=1).
template <int OUT_F32>
__global__ __launch_bounds__(512) void k_gemm_h(
    const unsigned short* __restrict__ X, const unsigned short* __restrict__ Bt,
    const float* __restrict__ bias, const float* __restrict__ dinvp,
    unsigned short* __restrict__ Ob, float* __restrict__ Of, int n) {
  __shared__ char lds[65536];
  const int flat = threadIdx.x;
  const int wave = flat >> 6, lane = flat & 63;
  const int l15 = lane & 15, q = lane >> 4;
  const int wM = wave >> 1, wN = wave & 1;
  const int rowBase = blockIdx.x * 128;
  const int colBase = wN * 64;

  auto stage = [&](int ks, int buf) {
    char* ldsA = lds + buf * 32768;
    char* ldsB = ldsA + 16384;
#pragma unroll
    for (int j = 0; j < 2; ++j) {
      int i = j * 512 + flat;
      int row = i >> 3, pslot = i & 7;
      int lslot = pslot ^ (row & 7);
      int rowc = rowBase + row; if (rowc >= n) rowc = n - 1;
      gload16((const char*)X + (size_t)rowc * 256 + ks * 128 + lslot * 16,
              ldsA + (j * 512 + wave * 64) * 16);
    }
#pragma unroll
    for (int j = 0; j < 2; ++j) {
      int i = j * 512 + flat;
      int col = i >> 3, pslot = i & 7;
      int lslot = pslot ^ (col & 7);
      gload16((const char*)Bt + (size_t)col * 256 + ks * 128 + lslot * 16,
              ldsB + (j * 512 + wave * 64) * 16);
    }
  };

  f32x4 acc[2][4];
#pragma unroll
  for (int i = 0; i < 2; ++i)
#pragma unroll
    for (int j = 0; j < 4; ++j) acc[i][j] = (f32x4){0.f, 0.f, 0.f, 0.f};

  stage(0, 0);
  stage(1, 1);

#pragma unroll
  for (int ks = 0; ks < 2; ++ks) {
    if (ks == 0) asm volatile("s_waitcnt vmcnt(4)" ::: "memory");
    else         asm volatile("s_waitcnt vmcnt(0)" ::: "memory");
    __builtin_amdgcn_s_barrier();
    char* ldsA = lds + ks * 32768;
    char* ldsB = ldsA + 16384;
#pragma unroll
    for (int k2 = 0; k2 < 2; ++k2) {
      bf16x8 a[2], b[4];
#pragma unroll
      for (int mt = 0; mt < 2; ++mt) {
        int row = wM * 32 + mt * 16 + l15;
        a[mt] = *(const bf16x8*)(ldsA + row * 128 + (((k2 * 4 + q) ^ (row & 7)) * 16));
      }
#pragma unroll
      for (int nt = 0; nt < 4; ++nt) {
        int col = colBase + nt * 16 + l15;
        b[nt] = *(const bf16x8*)(ldsB + col * 128 + (((k2 * 4 + q) ^ (col & 7)) * 16));
      }
#pragma unroll
      for (int mt = 0; mt < 2; ++mt)
#pragma unroll
        for (int nt = 0; nt < 4; ++nt)
          acc[mt][nt] = __builtin_amdgcn_mfma_f32_16x16x32_bf16(a[mt], b[nt], acc[mt][nt], 0, 0, 0);
    }
  }

#pragma unroll
  for (int mt = 0; mt < 2; ++mt) {
    float4 dv;
    if (!OUT_F32) dv = *(const float4*)(dinvp + rowBase + wM * 32 + mt * 16 + q * 4);
#pragma unroll
    for (int nt = 0; nt < 4; ++nt) {
      int col = colBase + nt * 16 + l15;
      float bb = OUT_F32 ? bias[col] : 0.f;
#pragma unroll
      for (int r = 0; r < 4; ++r) {
        int row = rowBase + wM * 32 + mt * 16 + q * 4 + r;
        if (row < n) {
          if (OUT_F32) {
            __builtin_nontemporal_store(acc[mt][nt][r] + bb, &Of[(size_t)row * 128 + col]);
          } else {
            float dvr = (r == 0) ? dv.x : (r == 1) ? dv.y : (r == 2) ? dv.z : dv.w;
            Ob[(size_t)row * 128 + col] = f2b(acc[mt][nt][r] * dvr);
          }
        }
      }
    }
  }
}

// ---------------- aggregation (wave per node, 4 edges/instr) ----------------
// grp = lane>>4 handles edge (j+grp); sub = lane&15 holds feats [sub*8, sub*8+8).
// h rows are pre-scaled by dinv[src]; coef = dg applied once at the end.

__device__ __forceinline__ void agg_edges4(
    const unsigned short* __restrict__ h, const int* __restrict__ csr_src,
    int beg, int end, int lane, int grp, int sub, float* acc) {
  for (int base = beg; base < end; base += 64) {
    int m = end - base; if (m > 64) m = 64;
    int idx_l = (base + lane < end) ? csr_src[base + lane] : 0;
    for (int j = 0; j < m; j += 16) {
      int s0 = __builtin_amdgcn_ds_bpermute((j + grp) << 2, idx_l);
      int s1 = __builtin_amdgcn_ds_bpermute((j + 4 + grp) << 2, idx_l);
      int s2 = __builtin_amdgcn_ds_bpermute((j + 8 + grp) << 2, idx_l);
      int s3 = __builtin_amdgcn_ds_bpermute((j + 12 + grp) << 2, idx_l);
      uint4 v0 = *(const uint4*)(h + (size_t)s0 * 128 + sub * 8);
      uint4 v1 = *(const uint4*)(h + (size_t)s1 * 128 + sub * 8);
      uint4 v2 = *(const uint4*)(h + (size_t)s2 * 128 + sub * 8);
      uint4 v3 = *(const uint4*)(h + (size_t)s3 * 128 + sub * 8);
      if (j + grp < m) {
        add2(acc[0], acc[1], v0.x); add2(acc[2], acc[3], v0.y);
        add2(acc[4], acc[5], v0.z); add2(acc[6], acc[7], v0.w);
      }
      if (j + 4 + grp < m) {
        add2(acc[0], acc[1], v1.x); add2(acc[2], acc[3], v1.y);
        add2(acc[4], acc[5], v1.z); add2(acc[6], acc[7], v1.w);
      }
      if (j + 8 + grp < m) {
        add2(acc[0], acc[1], v2.x); add2(acc[2], acc[3], v2.y);
        add2(acc[4], acc[5], v2.z); add2(acc[6], acc[7], v2.w);
      }
      if (j + 12 + grp < m) {
        add2(acc[0], acc[1], v3.x); add2(acc[2], acc[3], v3.y);
        add2(acc[4], acc[5], v3.z); add2(acc[6], acc[7], v3.w);
      }
    }
  }
}

__device__ __forceinline__ void grp_reduce(float* acc) {
#pragma unroll
  for (int i = 0; i < 8; ++i) {
    acc[i] += __shfl_xor(acc[i], 16);
    acc[i] += __shfl_xor(acc[i], 32);
  }
}

__global__ __launch_bounds__(256) void k_agg1(
    const unsigned short* __restrict__ h,   // dinv-scaled xW1 bf16 [n,128]
    const int* __restrict__ row_start, const int* __restrict__ csr_src,
    const float* __restrict__ dinv,
    const float* __restrict__ bias,         // b1
    unsigned short* __restrict__ hout, int n) {
  int gw = blockIdx.x * 4 + (threadIdx.x >> 6);
  int lane = threadIdx.x & 63;
  int grp = lane >> 4, sub = lane & 15;
  if (gw >= n) return;
  int beg = row_start[gw], end = row_start[gw + 1];
  float acc[8] = {0.f, 0.f, 0.f, 0.f, 0.f, 0.f, 0.f, 0.f};
  agg_edges4(h, csr_src, beg, end, lane, grp, sub, acc);
  grp_reduce(acc);
  if (grp == 0) {
    float dg = dinv[gw];
    uint4 sv = *(const uint4*)(h + (size_t)gw * 128 + sub * 8);  // self (pre-scaled)
    add2(acc[0], acc[1], sv.x); add2(acc[2], acc[3], sv.y);
    add2(acc[4], acc[5], sv.z); add2(acc[6], acc[7], sv.w);
    float4 b0 = *(const float4*)(bias + sub * 8);
    float4 b1v = *(const float4*)(bias + sub * 8 + 4);
    float a[8];
    a[0] = fmaxf(acc[0] * dg + b0.x, 0.f); a[1] = fmaxf(acc[1] * dg + b0.y, 0.f);
    a[2] = fmaxf(acc[2] * dg + b0.z, 0.f); a[3] = fmaxf(acc[3] * dg + b0.w, 0.f);
    a[4] = fmaxf(acc[4] * dg + b1v.x, 0.f); a[5] = fmaxf(acc[5] * dg + b1v.y, 0.f);
    a[6] = fmaxf(acc[6] * dg + b1v.z, 0.f); a[7] = fmaxf(acc[7] * dg + b1v.w, 0.f);
    uint4 o;
    o.x = pack2(a[0], a[1]); o.y = pack2(a[2], a[3]);
    o.z = pack2(a[4], a[5]); o.w = pack2(a[6], a[7]);
    *(uint4*)(hout + (size_t)gw * 128 + sub * 8) = o;
  }
}

__global__ __launch_bounds__(256) void k_agg2_epi(
    const unsigned short* __restrict__ h,   // dinv-scaled h1@W2 bf16 [n,128]
    const int* __restrict__ row_start, const int* __restrict__ csr_src,
    const float* __restrict__ dinv,
    const float* __restrict__ bias,    // b2
    float* res_out1,                   // in: x@Wd+bd; out: log_softmax
    const float* __restrict__ wdeg, const float* __restrict__ bdeg,
    float* __restrict__ out2,          // [n]
    unsigned short* __restrict__ hf,   // h bf16 [n,128]
    int n) {
  int gw = blockIdx.x * 4 + (threadIdx.x >> 6);
  int lane = threadIdx.x & 63;
  int grp = lane >> 4, sub = lane & 15;
  if (gw >= n) return;
  int beg = row_start[gw], end = row_start[gw + 1];
  float acc[8] = {0.f, 0.f, 0.f, 0.f, 0.f, 0.f, 0.f, 0.f};
  agg_edges4(h, csr_src, beg, end, lane, grp, sub, acc);
  grp_reduce(acc);
  if (grp == 0) {
    float dg = dinv[gw];
    uint4 sv = *(const uint4*)(h + (size_t)gw * 128 + sub * 8);
    add2(acc[0], acc[1], sv.x); add2(acc[2], acc[3], sv.y);
    add2(acc[4], acc[5], sv.z); add2(acc[6], acc[7], sv.w);
    float4 b0 = *(const float4*)(bias + sub * 8);
    float4 b1v = *(const float4*)(bias + sub * 8 + 4);
    float4 r0 = *(const float4*)(res_out1 + (size_t)gw * 128 + sub * 8);
    float4 r1 = *(const float4*)(res_out1 + (size_t)gw * 128 + sub * 8 + 4);
    float a[8];
    a[0] = acc[0] * dg + b0.x + r0.x; a[1] = acc[1] * dg + b0.y + r0.y;
    a[2] = acc[2] * dg + b0.z + r0.z; a[3] = acc[3] * dg + b0.w + r0.w;
    a[4] = acc[4] * dg + b1v.x + r1.x; a[5] = acc[5] * dg + b1v.y + r1.y;
    a[6] = acc[6] * dg + b1v.z + r1.z; a[7] = acc[7] * dg + b1v.w + r1.w;
    uint4 o;
    o.x = pack2(a[0], a[1]); o.y = pack2(a[2], a[3]);
    o.z = pack2(a[4], a[5]); o.w = pack2(a[6], a[7]);
    *(uint4*)(hf + (size_t)gw * 128 + sub * 8) = o;
    // result2 (degree head)
    float4 w0 = *(const float4*)(wdeg + sub * 8);
    float4 w1 = *(const float4*)(wdeg + sub * 8 + 4);
    float t = a[0] * w0.x + a[1] * w0.y + a[2] * w0.z + a[3] * w0.w +
              a[4] * w1.x + a[5] * w1.y + a[6] * w1.z + a[7] * w1.w;
#pragma unroll
    for (int mk = 8; mk >= 1; mk >>= 1) t += __shfl_xor(t, mk);
    if (sub == 0) __builtin_nontemporal_store(t + bdeg[0], out2 + gw);
    // log_softmax
    float mx = a[0];
#pragma unroll
    for (int i = 1; i < 8; ++i) mx = fmaxf(mx, a[i]);
#pragma unroll
    for (int mk = 8; mk >= 1; mk >>= 1) mx = fmaxf(mx, __shfl_xor(mx, mk));
    float l = 0.f;
#pragma unroll
    for (int i = 0; i < 8; ++i) l += __expf(a[i] - mx);
#pragma unroll
    for (int mk = 8; mk >= 1; mk >>= 1) l += __shfl_xor(l, mk);
    float ls = mx + __logf(l);
    f32x4 o0 = {a[0] - ls, a[1] - ls, a[2] - ls, a[3] - ls};
    f32x4 o1 = {a[4] - ls, a[5] - ls, a[6] - ls, a[7] - ls};
    __builtin_nontemporal_store(o0, (f32x4*)(res_out1 + (size_t)gw * 128 + sub * 8));
    __builtin_nontemporal_store(o1, (f32x4*)(res_out1 + (size_t)gw * 128 + sub * 8 + 4));
  }
}

// ---------------- launch ----------------

extern "C" void kernel_launch(void* const* d_in, const int* in_sizes, int n_in,
                              void* d_out, int out_size, void* d_ws, size_t ws_size,
                              hipStream_t stream) {
  const float* x   = (const float*)d_in[0];
  const int*   ei  = (const int*)d_in[1];
  const float* W1  = (const float*)d_in[2];
  const float* b1  = (const float*)d_in[3];
  const float* W2  = (const float*)d_in[4];
  const float* b2  = (const float*)d_in[5];
  const float* Wd  = (const float*)d_in[6];
  const float* bd  = (const float*)d_in[7];
  const float* Wdg = (const float*)d_in[8];
  const float* bdg = (const float*)d_in[9];
  const float* W3  = (const float*)d_in[10];
  const float* b3  = (const float*)d_in[11];

  const int N = in_sizes[0] / 256;
  const int E = in_sizes[1] / 2;

  // ---- workspace (~35 MB) ----
  char* w = (char*)d_ws;
  auto alloc = [&](size_t bytes) {
    char* p = w;
    w += (bytes + 255) & ~(size_t)255;
    return p;
  };
  unsigned short* W1t  = (unsigned short*)alloc((size_t)256 * 128 * 2);
  unsigned short* Wdt  = (unsigned short*)alloc((size_t)256 * 128 * 2);
  unsigned short* W2t  = (unsigned short*)alloc((size_t)128 * 128 * 2);
  unsigned short* W3t  = (unsigned short*)alloc((size_t)128 * 128 * 2);
  unsigned short* bufC = (unsigned short*)alloc((size_t)N * 128 * 2);  // h1/h bf16; pairs scratch pre-agg1
  int*   deg      = (int*)alloc((size_t)N * 4);
  float* dinv     = (float*)alloc((size_t)(N + 128) * 4);  // padded for GEMM-tail float4 reads
  int*   row_start= (int*)alloc((size_t)(N + 1) * 4);
  int*   cursor   = (int*)alloc((size_t)N * 4);
  int*   partials = (int*)alloc(4096);
  int*   pprefix  = (int*)alloc(4096);
  int*   csr_src  = (int*)alloc((size_t)E * 4);
  int*   bcnt     = (int*)alloc(2048);            // 256 bucket counts + ovf_cnt (zeroed in wtrans4)
  int*   ovf_cnt  = bcnt + 256;
  int2*  ovf      = (int2*)alloc((size_t)OVF_CAP * 8);

  // ---- d_out regions; out3 doubles as bf16 scratch bufA ----
  float* out1 = (float*)d_out;               // residual, then log_softmax
  float* out2 = out1 + (size_t)N * 128;
  float* out3 = out2 + (size_t)N;
  unsigned short* bufA = (unsigned short*)out3;  // xW1 / h1W2 bf16 (dead before out3)

  // pairs intermediate reuses bufC (dead until k_agg1)
  const int nbuck = CDIV(N, 512);                // <=256 for N<=131072
  int cap = (E / nbuck) + (E / nbuck) / 2;       // 1.5x avg bucket size
  cap = (cap + 255) & ~255;
  size_t bufC_bytes = (size_t)N * 128 * 2;
  if ((size_t)nbuck * cap * 8 > bufC_bytes)
    cap = (int)(bufC_bytes / ((size_t)nbuck * 8));
  int2* pairs = (int2*)bufC;

  // wtrans + deg/bcnt zero-init (folded; replaces 2 memsets)
  k_wtrans4<<<CDIV(98304 + N + 512, 256), 256, 0, stream>>>(
      W1, Wd, W2, W3, W1t, Wdt, W2t, W3t, deg, bcnt, N);

  // deg count + pair binning (one ei pass)
  k_binA<<<CDIV(E, BIN_CHUNK), 256, 0, stream>>>(ei, E, nbuck, cap, deg, pairs,
                                                 bcnt, ovf, ovf_cnt);

  // dinv before gemm_x2 (O1 rows scaled by dinv)
  const int nb = CDIV(N, 2048);
  k_scan1<<<nb, 256, 0, stream>>>(deg, row_start, partials, dinv, N);
  k_scan2<<<1, 64, 0, stream>>>(partials, pprefix, nb);
  k_scan3<<<CDIV(N, 256), 256, 0, stream>>>(pprefix, row_start, cursor, N, E);

  // fused x@W1*dinv -> bufA (bf16), x@Wd+bd -> out1 (fp32 residual)
  k_gemm_x2<<<CDIV(N, 128), 512, 0, stream>>>(x, W1t, Wdt, bd, dinv, bufA, out1, N);

  // bucket-local scatter -> csr_src (LDS cursors when no overflow)
  k_binB<<<nbuck + 8, 256, 0, stream>>>(pairs, bcnt, nbuck, cap, ovf, ovf_cnt,
                                        cursor, csr_src, N);

  // layer 1: aggregate dinv-scaled xW1, *dg, +b1, relu -> h1 (bufC)
  k_agg1<<<CDIV(N, 4), 256, 0, stream>>>(bufA, row_start, csr_src, dinv, b1, bufC, N);

  // h1 @ W2, rows scaled by dinv -> bufA
  k_gemm_h<0><<<CDIV(N, 128), 512, 0, stream>>>(bufC, W2t, nullptr, dinv, bufA, nullptr, N);

  // layer 2 aggregate + b2 + residual; log_softmax -> out1, deg head -> out2,
  // h bf16 -> bufC
  k_agg2_epi<<<CDIV(N, 4), 256, 0, stream>>>(bufA, row_start, csr_src, dinv,
                                             b2, out1, Wdg, bdg, out2, bufC, N);

  // result3 = h @ W3 + b3 -> out3
  k_gemm_h<1><<<CDIV(N, 128), 512, 0, stream>>>(bufC, W3t, b3, nullptr, nullptr, out3, N);
}

// Round 9
// 497.327 us; speedup vs baseline: 1.6275x; 1.0058x over previous
//
#include <hip/hip_runtime.h>

// GNN_22505628631761: 2-layer GCN (sym-norm, self-loops) + residual + 3 outputs.
// fp32 in/out; bf16 MFMA GEMMs + bf16 h buffers internally.
// R10: GEMMs LDS-staged + counted vmcnt; aggs 4-edges/instr.
// R13: binB LDS-cursors; deg/bcnt zeroing folded into wtrans4 (500us).
// R14: gemm_x2 behavior law established (dur = hbm_bytes/1.5TB/s, schedule-
//      invariant) -> cut bytes: (a) residual x@Wd+bd stored BF16 (25.6 vs
//      51.2MB) in out3-region 2nd half (dies before gemm_h<1> writes out3);
//      agg2 reads bf16 residual. Saves ~51MB round trip. (b) scan2 merged
//      into scan3 (per-thread prefix over <=48 partials), -1 dispatch.

typedef __attribute__((ext_vector_type(8))) short bf16x8;
typedef __attribute__((ext_vector_type(4))) float f32x4;

#define CDIV(a, b) (((a) + (b) - 1) / (b))

#define GLOBAL_AS __attribute__((address_space(1)))
#define LDS_AS __attribute__((address_space(3)))

__device__ __forceinline__ void gload16(const void* g, void* l) {
  __builtin_amdgcn_global_load_lds((const GLOBAL_AS unsigned int*)g,
                                   (LDS_AS unsigned int*)l, 16, 0, 0);
}

__device__ __forceinline__ float b2f(unsigned short u) {
  union { unsigned int i; float f; } x; x.i = ((unsigned int)u) << 16; return x.f;
}
__device__ __forceinline__ unsigned short f2b(float f) {
  union { float f; unsigned int i; } x; x.f = f;
  unsigned int r = x.i + 0x7fffu + ((x.i >> 16) & 1u);  // RNE
  return (unsigned short)(r >> 16);
}
// add both bf16 halves of u into a0 (low) / a1 (high)
__device__ __forceinline__ void add2(float& a0, float& a1, unsigned int u) {
  union { unsigned int i; float f; } lo, hi;
  lo.i = u << 16; hi.i = u & 0xffff0000u;
  a0 += lo.f; a1 += hi.f;
}
__device__ __forceinline__ unsigned int pack2(float lo, float hi) {
  return __builtin_amdgcn_perm(__float_as_uint(hi) + 0x8000u,
                               __float_as_uint(lo) + 0x8000u, 0x07060302u);
}

// ---------------- setup kernels ----------------

// all four W [K][N] fp32 -> Wt [N][K] bf16, plus deg/bcnt zero-init tail
__global__ void k_wtrans4(const float* __restrict__ W1, const float* __restrict__ Wd,
                          const float* __restrict__ W2, const float* __restrict__ W3,
                          unsigned short* __restrict__ W1t, unsigned short* __restrict__ Wdt,
                          unsigned short* __restrict__ W2t, unsigned short* __restrict__ W3t,
                          int* __restrict__ deg, int* __restrict__ bcnt, int n) {
  int idx = blockIdx.x * blockDim.x + threadIdx.x;
  if (idx >= 98304) {
    idx -= 98304;
    if (idx < n) deg[idx] = 0;
    else if (idx - n < 512) bcnt[idx - n] = 0;
    return;
  }
  const float* in; unsigned short* out; int K, N;
  if (idx < 32768)       { in = W1; out = W1t; K = 256; N = 128; }
  else if (idx < 65536)  { in = Wd; out = Wdt; K = 256; N = 128; idx -= 32768; }
  else if (idx < 81920)  { in = W2; out = W2t; K = 128; N = 128; idx -= 65536; }
  else                   { in = W3; out = W3t; K = 128; N = 128; idx -= 81920; }
  int k = idx / N, nn = idx - k * N;
  out[nn * K + k] = f2b(in[idx]);
}

// exclusive scan over deg (2048/block) + dinv = rsqrt(deg+1)
__global__ void k_scan1(const int* __restrict__ deg, int* __restrict__ lscan,
                        int* __restrict__ partials, float* __restrict__ dinv, int n) {
  __shared__ int sd[256];
  int tid = threadIdx.x;
  int base = blockIdx.x * 2048 + tid * 8;
  int v[8]; int tsum = 0;
#pragma unroll
  for (int i = 0; i < 8; ++i) {
    int idx = base + i;
    int xv = (idx < n) ? deg[idx] : 0;
    v[i] = xv; tsum += xv;
    if (idx < n) dinv[idx] = 1.0f / sqrtf((float)xv + 1.0f);
  }
  sd[tid] = tsum;
  __syncthreads();
  for (int off = 1; off < 256; off <<= 1) {
    int t = (tid >= off) ? sd[tid - off] : 0;
    __syncthreads();
    sd[tid] += t;
    __syncthreads();
  }
  int run = sd[tid] - tsum;
#pragma unroll
  for (int i = 0; i < 8; ++i) {
    int idx = base + i;
    if (idx < n) lscan[idx] = run;
    run += v[i];
  }
  if (tid == 255) partials[blockIdx.x] = sd[255];
}

// finalize row_start/cursor; per-thread prefix over partials (<=48 iters, L1-hot)
__global__ void k_scan3(const int* __restrict__ partials, int* row_start,
                        int* __restrict__ cursor, int n, int E) {
  int idx = blockIdx.x * blockDim.x + threadIdx.x;
  if (idx >= n) return;
  int g = idx >> 11;
  int pre = 0;
  for (int i = 0; i < g; ++i) pre += partials[i];
  int v = row_start[idx] + pre;
  row_start[idx] = v;
  cursor[idx] = v;
  if (idx == 0) row_start[n] = E;
}

// ---------------- 2-pass radix binning ----------------

#define BIN_CHUNK 4096  // edges per block in pass A (16/thread)
#define OVF_CAP 65536

__global__ __launch_bounds__(256) void k_binA(
    const int* __restrict__ ei, int E, int nbuck, int cap,
    int* __restrict__ deg, int2* __restrict__ pairs, int* __restrict__ bcnt,
    int2* __restrict__ ovf, int* __restrict__ ovf_cnt) {
  __shared__ int lcnt[256];
  __shared__ int lbase[256];
  int tid = threadIdx.x;
  for (int i = tid; i < nbuck; i += 256) lcnt[i] = 0;
  __syncthreads();
  int base_e = blockIdx.x * BIN_CHUNK;
  int src[16], dst[16], lofs[16];
#pragma unroll
  for (int i = 0; i < 16; ++i) {
    int e = base_e + i * 256 + tid;
    if (e < E) {
      int s = ei[e], d = ei[E + e];
      src[i] = s; dst[i] = d;
      atomicAdd(&deg[d], 1);
      lofs[i] = atomicAdd(&lcnt[d >> 9], 1);
    } else {
      dst[i] = -1;
    }
  }
  __syncthreads();
  for (int b = tid; b < nbuck; b += 256)
    lbase[b] = atomicAdd(&bcnt[b], lcnt[b]);
  __syncthreads();
#pragma unroll
  for (int i = 0; i < 16; ++i) {
    if (dst[i] < 0) continue;
    int b = dst[i] >> 9;
    int gpos = lbase[b] + lofs[i];
    if (gpos < cap) {
      pairs[(size_t)b * cap + gpos] = make_int2(src[i], dst[i]);
    } else {
      int op = atomicAdd(ovf_cnt, 1);
      if (op < OVF_CAP) ovf[op] = make_int2(src[i], dst[i]);
    }
  }
}

__global__ __launch_bounds__(256) void k_binB(
    const int2* __restrict__ pairs, const int* __restrict__ bcnt,
    int nbuck, int cap,
    const int2* __restrict__ ovf, const int* __restrict__ ovf_cnt,
    int* __restrict__ cursor, int* __restrict__ csr_src, int n) {
  int ov = *ovf_cnt;
  if ((int)blockIdx.x < nbuck) {
    int b = blockIdx.x;
    int cnt = bcnt[b]; if (cnt > cap) cnt = cap;
    const int2* p = pairs + (size_t)b * cap;
    if (ov == 0) {
      // bucket-private cursors in LDS (bucket = 512 nodes)
      __shared__ int lcur[512];
      int nbase = b << 9;
      for (int i = threadIdx.x; i < 512; i += 256) {
        int node = nbase + i;
        lcur[i] = (node < n) ? cursor[node] : 0;
      }
      __syncthreads();
      for (int i = threadIdx.x; i < cnt; i += 256) {
        int2 e = p[i];
        int pos = atomicAdd(&lcur[e.y - nbase], 1);
        csr_src[pos] = e.x;
      }
    } else {
      for (int i = threadIdx.x; i < cnt; i += 256) {
        int2 e = p[i];
        int pos = atomicAdd(&cursor[e.y], 1);
        csr_src[pos] = e.x;
      }
    }
  } else {
    int total = ov; if (total > OVF_CAP) total = OVF_CAP;
    int start = (blockIdx.x - nbuck) * 256 + threadIdx.x;
    for (int i = start; i < total; i += 8 * 256) {
      int2 e = ovf[i];
      int pos = atomicAdd(&cursor[e.y], 1);
      csr_src[pos] = e.x;
    }
  }
}

// ---------------- GEMMs (MFMA bf16 16x16x32, LDS-staged) ----------------
// Block 128 rows x 128 cols, 512 thr (8 waves, 4x2), wave tile 32x64 (2x4).
// LDS dest linear (global_load_lds), source pre-swizzled slot^=(row&7).
// C/D: col=lane&15, row=(lane>>4)*4+reg.

__global__ __launch_bounds__(512) void k_gemm_x2(
    const float* __restrict__ X,             // [n,256] fp32
    const unsigned short* __restrict__ B1t,  // [128,256] bf16 = W1^T
    const unsigned short* __restrict__ B2t,  // [128,256] bf16 = Wd^T
    const float* __restrict__ bias2,         // bd
    const float* __restrict__ dinvp,         // [n+pad] row scale for O1
    unsigned short* __restrict__ O1,         // xW1*dinv bf16 [n,128]
    unsigned short* __restrict__ O2,         // residual bf16 [n,128]
    int n) {
  __shared__ char lds[65536];  // 2 x (A 16KB + B 16KB)
  const int flat = threadIdx.x;
  const int wave = flat >> 6, lane = flat & 63;
  const int l15 = lane & 15, q = lane >> 4;
  const int wM = wave >> 1, wN = wave & 1;
  const int rowBase = blockIdx.x * 128;
  const int colBase = wN * 64;

  auto stage = [&](int kb, int buf) {
    char* ldsA = lds + buf * 32768;
    char* ldsB = ldsA + 16384;
    const char* Xb = (const char*)X;
#pragma unroll
    for (int j = 0; j < 2; ++j) {
      int i = j * 512 + flat;
      int row = i >> 3, pslot = i & 7;
      int lslot = pslot ^ (row & 7);
      int rowc = rowBase + row; if (rowc >= n) rowc = n - 1;
      gload16(Xb + (size_t)rowc * 1024 + (size_t)(kb * 128 + lslot * 16),
              ldsA + (j * 512 + wave * 64) * 16);
    }
#pragma unroll
    for (int j = 0; j < 2; ++j) {
      int i = j * 512 + flat;
      int col = i >> 3, pslot = i & 7;
      int lslot = pslot ^ (col & 7);
      const char* src = (lslot >= 4) ? (const char*)B2t : (const char*)B1t;
      gload16(src + (size_t)col * 512 + kb * 64 + (lslot & 3) * 16,
              ldsB + (j * 512 + wave * 64) * 16);
    }
  };

  f32x4 acc1[2][4], acc2[2][4];
#pragma unroll
  for (int i = 0; i < 2; ++i)
#pragma unroll
    for (int j = 0; j < 4; ++j) {
      acc1[i][j] = (f32x4){0.f, 0.f, 0.f, 0.f};
      acc2[i][j] = (f32x4){0.f, 0.f, 0.f, 0.f};
    }

  stage(0, 0);
  stage(1, 1);

#pragma unroll
  for (int kb = 0; kb < 8; ++kb) {
    int cur = kb & 1;
    if (kb < 7) asm volatile("s_waitcnt vmcnt(4)" ::: "memory");
    else        asm volatile("s_waitcnt vmcnt(0)" ::: "memory");
    __builtin_amdgcn_s_barrier();
    char* ldsA = lds + cur * 32768;
    char* ldsB = ldsA + 16384;
    bf16x8 a[2], b1v[4], b2v[4];
#pragma unroll
    for (int mt = 0; mt < 2; ++mt) {
      int row = wM * 32 + mt * 16 + l15;
      uint4 lo = *(const uint4*)(ldsA + row * 128 + (((2 * q) ^ (row & 7)) * 16));
      uint4 hi = *(const uint4*)(ldsA + row * 128 + (((2 * q + 1) ^ (row & 7)) * 16));
      union { bf16x8 v; unsigned int u[4]; } r;
      r.u[0] = __builtin_amdgcn_perm(lo.y + 0x8000u, lo.x + 0x8000u, 0x07060302u);
      r.u[1] = __builtin_amdgcn_perm(lo.w + 0x8000u, lo.z + 0x8000u, 0x07060302u);
      r.u[2] = __builtin_amdgcn_perm(hi.y + 0x8000u, hi.x + 0x8000u, 0x07060302u);
      r.u[3] = __builtin_amdgcn_perm(hi.w + 0x8000u, hi.z + 0x8000u, 0x07060302u);
      a[mt] = r.v;
    }
#pragma unroll
    for (int nt = 0; nt < 4; ++nt) {
      int col = colBase + nt * 16 + l15;
      b1v[nt] = *(const bf16x8*)(ldsB + col * 128 + ((q ^ (col & 7)) * 16));
      b2v[nt] = *(const bf16x8*)(ldsB + col * 128 + (((4 + q) ^ (col & 7)) * 16));
    }
#pragma unroll
    for (int mt = 0; mt < 2; ++mt)
#pragma unroll
      for (int nt = 0; nt < 4; ++nt) {
        acc1[mt][nt] = __builtin_amdgcn_mfma_f32_16x16x32_bf16(a[mt], b1v[nt], acc1[mt][nt], 0, 0, 0);
        acc2[mt][nt] = __builtin_amdgcn_mfma_f32_16x16x32_bf16(a[mt], b2v[nt], acc2[mt][nt], 0, 0, 0);
      }
    asm volatile("s_waitcnt lgkmcnt(0)" ::: "memory");
    __builtin_amdgcn_s_barrier();
    if (kb < 6) stage(kb + 2, cur);
  }

#pragma unroll
  for (int mt = 0; mt < 2; ++mt) {
    float4 dv = *(const float4*)(dinvp + rowBase + wM * 32 + mt * 16 + q * 4);
#pragma unroll
    for (int nt = 0; nt < 4; ++nt) {
      int col = colBase + nt * 16 + l15;
      float bb = bias2[col];
#pragma unroll
      for (int r = 0; r < 4; ++r) {
        int row = rowBase + wM * 32 + mt * 16 + q * 4 + r;
        if (row < n) {
          float dvr = (r == 0) ? dv.x : (r == 1) ? dv.y : (r == 2) ? dv.z : dv.w;
          O1[(size_t)row * 128 + col] = f2b(acc1[mt][nt][r] * dvr);
          O2[(size_t)row * 128 + col] = f2b(acc2[mt][nt][r] + bb);
        }
      }
    }
  }
}

// A bf16 [n,128] @ Bt bf16 [128,128] -> bf16*dinv (OUT_F32=0) or fp32+bias (=1).
template <int OUT_F32>
__global__ __launch_bounds__(512) void k_gemm_h(
    const unsigned short* __restrict__ X, const unsigned short* __restrict__ Bt,
    const float* __restrict__ bias, const float* __restrict__ dinvp,
    unsigned short* __restrict__ Ob, float* __restrict__ Of, int n) {
  __shared__ char lds[65536];
  const int flat = threadIdx.x;
  const int wave = flat >> 6, lane = flat & 63;
  const int l15 = lane & 15, q = lane >> 4;
  const int wM = wave >> 1, wN = wave & 1;
  const int rowBase = blockIdx.x * 128;
  const int colBase = wN * 64;

  auto stage = [&](int ks, int buf) {
    char* ldsA = lds + buf * 32768;
    char* ldsB = ldsA + 16384;
#pragma unroll
    for (int j = 0; j < 2; ++j) {
      int i = j * 512 + flat;
      int row = i >> 3, pslot = i & 7;
      int lslot = pslot ^ (row & 7);
      int rowc = rowBase + row; if (rowc >= n) rowc = n - 1;
      gload16((const char*)X + (size_t)rowc * 256 + ks * 128 + lslot * 16,
              ldsA + (j * 512 + wave * 64) * 16);
    }
#pragma unroll
    for (int j = 0; j < 2; ++j) {
      int i = j * 512 + flat;
      int col = i >> 3, pslot = i & 7;
      int lslot = pslot ^ (col & 7);
      gload16((const char*)Bt + (size_t)col * 256 + ks * 128 + lslot * 16,
              ldsB + (j * 512 + wave * 64) * 16);
    }
  };

  f32x4 acc[2][4];
#pragma unroll
  for (int i = 0; i < 2; ++i)
#pragma unroll
    for (int j = 0; j < 4; ++j) acc[i][j] = (f32x4){0.f, 0.f, 0.f, 0.f};

  stage(0, 0);
  stage(1, 1);

#pragma unroll
  for (int ks = 0; ks < 2; ++ks) {
    if (ks == 0) asm volatile("s_waitcnt vmcnt(4)" ::: "memory");
    else         asm volatile("s_waitcnt vmcnt(0)" ::: "memory");
    __builtin_amdgcn_s_barrier();
    char* ldsA = lds + ks * 32768;
    char* ldsB = ldsA + 16384;
#pragma unroll
    for (int k2 = 0; k2 < 2; ++k2) {
      bf16x8 a[2], b[4];
#pragma unroll
      for (int mt = 0; mt < 2; ++mt) {
        int row = wM * 32 + mt * 16 + l15;
        a[mt] = *(const bf16x8*)(ldsA + row * 128 + (((k2 * 4 + q) ^ (row & 7)) * 16));
      }
#pragma unroll
      for (int nt = 0; nt < 4; ++nt) {
        int col = colBase + nt * 16 + l15;
        b[nt] = *(const bf16x8*)(ldsB + col * 128 + (((k2 * 4 + q) ^ (col & 7)) * 16));
      }
#pragma unroll
      for (int mt = 0; mt < 2; ++mt)
#pragma unroll
        for (int nt = 0; nt < 4; ++nt)
          acc[mt][nt] = __builtin_amdgcn_mfma_f32_16x16x32_bf16(a[mt], b[nt], acc[mt][nt], 0, 0, 0);
    }
  }

#pragma unroll
  for (int mt = 0; mt < 2; ++mt) {
    float4 dv;
    if (!OUT_F32) dv = *(const float4*)(dinvp + rowBase + wM * 32 + mt * 16 + q * 4);
#pragma unroll
    for (int nt = 0; nt < 4; ++nt) {
      int col = colBase + nt * 16 + l15;
      float bb = OUT_F32 ? bias[col] : 0.f;
#pragma unroll
      for (int r = 0; r < 4; ++r) {
        int row = rowBase + wM * 32 + mt * 16 + q * 4 + r;
        if (row < n) {
          if (OUT_F32) {
            __builtin_nontemporal_store(acc[mt][nt][r] + bb, &Of[(size_t)row * 128 + col]);
          } else {
            float dvr = (r == 0) ? dv.x : (r == 1) ? dv.y : (r == 2) ? dv.z : dv.w;
            Ob[(size_t)row * 128 + col] = f2b(acc[mt][nt][r] * dvr);
          }
        }
      }
    }
  }
}

// ---------------- aggregation (wave per node, 4 edges/instr) ----------------
// grp = lane>>4 handles edge (j+grp); sub = lane&15 holds feats [sub*8, sub*8+8).
// h rows are pre-scaled by dinv[src]; coef = dg applied once at the end.

__device__ __forceinline__ void agg_edges4(
    const unsigned short* __restrict__ h, const int* __restrict__ csr_src,
    int beg, int end, int lane, int grp, int sub, float* acc) {
  for (int base = beg; base < end; base += 64) {
    int m = end - base; if (m > 64) m = 64;
    int idx_l = (base + lane < end) ? csr_src[base + lane] : 0;
    for (int j = 0; j < m; j += 16) {
      int s0 = __builtin_amdgcn_ds_bpermute((j + grp) << 2, idx_l);
      int s1 = __builtin_amdgcn_ds_bpermute((j + 4 + grp) << 2, idx_l);
      int s2 = __builtin_amdgcn_ds_bpermute((j + 8 + grp) << 2, idx_l);
      int s3 = __builtin_amdgcn_ds_bpermute((j + 12 + grp) << 2, idx_l);
      uint4 v0 = *(const uint4*)(h + (size_t)s0 * 128 + sub * 8);
      uint4 v1 = *(const uint4*)(h + (size_t)s1 * 128 + sub * 8);
      uint4 v2 = *(const uint4*)(h + (size_t)s2 * 128 + sub * 8);
      uint4 v3 = *(const uint4*)(h + (size_t)s3 * 128 + sub * 8);
      if (j + grp < m) {
        add2(acc[0], acc[1], v0.x); add2(acc[2], acc[3], v0.y);
        add2(acc[4], acc[5], v0.z); add2(acc[6], acc[7], v0.w);
      }
      if (j + 4 + grp < m) {
        add2(acc[0], acc[1], v1.x); add2(acc[2], acc[3], v1.y);
        add2(acc[4], acc[5], v1.z); add2(acc[6], acc[7], v1.w);
      }
      if (j + 8 + grp < m) {
        add2(acc[0], acc[1], v2.x); add2(acc[2], acc[3], v2.y);
        add2(acc[4], acc[5], v2.z); add2(acc[6], acc[7], v2.w);
      }
      if (j + 12 + grp < m) {
        add2(acc[0], acc[1], v3.x); add2(acc[2], acc[3], v3.y);
        add2(acc[4], acc[5], v3.z); add2(acc[6], acc[7], v3.w);
      }
    }
  }
}

__device__ __forceinline__ void grp_reduce(float* acc) {
#pragma unroll
  for (int i = 0; i < 8; ++i) {
    acc[i] += __shfl_xor(acc[i], 16);
    acc[i] += __shfl_xor(acc[i], 32);
  }
}

__global__ __launch_bounds__(256) void k_agg1(
    const unsigned short* __restrict__ h,   // dinv-scaled xW1 bf16 [n,128]
    const int* __restrict__ row_start, const int* __restrict__ csr_src,
    const float* __restrict__ dinv,
    const float* __restrict__ bias,         // b1
    unsigned short* __restrict__ hout, int n) {
  int gw = blockIdx.x * 4 + (threadIdx.x >> 6);
  int lane = threadIdx.x & 63;
  int grp = lane >> 4, sub = lane & 15;
  if (gw >= n) return;
  int beg = row_start[gw], end = row_start[gw + 1];
  float acc[8] = {0.f, 0.f, 0.f, 0.f, 0.f, 0.f, 0.f, 0.f};
  agg_edges4(h, csr_src, beg, end, lane, grp, sub, acc);
  grp_reduce(acc);
  if (grp == 0) {
    float dg = dinv[gw];
    uint4 sv = *(const uint4*)(h + (size_t)gw * 128 + sub * 8);  // self (pre-scaled)
    add2(acc[0], acc[1], sv.x); add2(acc[2], acc[3], sv.y);
    add2(acc[4], acc[5], sv.z); add2(acc[6], acc[7], sv.w);
    float4 b0 = *(const float4*)(bias + sub * 8);
    float4 b1v = *(const float4*)(bias + sub * 8 + 4);
    float a[8];
    a[0] = fmaxf(acc[0] * dg + b0.x, 0.f); a[1] = fmaxf(acc[1] * dg + b0.y, 0.f);
    a[2] = fmaxf(acc[2] * dg + b0.z, 0.f); a[3] = fmaxf(acc[3] * dg + b0.w, 0.f);
    a[4] = fmaxf(acc[4] * dg + b1v.x, 0.f); a[5] = fmaxf(acc[5] * dg + b1v.y, 0.f);
    a[6] = fmaxf(acc[6] * dg + b1v.z, 0.f); a[7] = fmaxf(acc[7] * dg + b1v.w, 0.f);
    uint4 o;
    o.x = pack2(a[0], a[1]); o.y = pack2(a[2], a[3]);
    o.z = pack2(a[4], a[5]); o.w = pack2(a[6], a[7]);
    *(uint4*)(hout + (size_t)gw * 128 + sub * 8) = o;
  }
}

__global__ __launch_bounds__(256) void k_agg2_epi(
    const unsigned short* __restrict__ h,   // dinv-scaled h1@W2 bf16 [n,128]
    const int* __restrict__ row_start, const int* __restrict__ csr_src,
    const float* __restrict__ dinv,
    const float* __restrict__ bias,    // b2
    const unsigned short* __restrict__ resb,  // residual bf16 [n,128]
    float* __restrict__ out1,          // log_softmax out
    const float* __restrict__ wdeg, const float* __restrict__ bdeg,
    float* __restrict__ out2,          // [n]
    unsigned short* __restrict__ hf,   // h bf16 [n,128]
    int n) {
  int gw = blockIdx.x * 4 + (threadIdx.x >> 6);
  int lane = threadIdx.x & 63;
  int grp = lane >> 4, sub = lane & 15;
  if (gw >= n) return;
  int beg = row_start[gw], end = row_start[gw + 1];
  float acc[8] = {0.f, 0.f, 0.f, 0.f, 0.f, 0.f, 0.f, 0.f};
  agg_edges4(h, csr_src, beg, end, lane, grp, sub, acc);
  grp_reduce(acc);
  if (grp == 0) {
    float dg = dinv[gw];
    uint4 sv = *(const uint4*)(h + (size_t)gw * 128 + sub * 8);
    add2(acc[0], acc[1], sv.x); add2(acc[2], acc[3], sv.y);
    add2(acc[4], acc[5], sv.z); add2(acc[6], acc[7], sv.w);
    float4 b0 = *(const float4*)(bias + sub * 8);
    float4 b1v = *(const float4*)(bias + sub * 8 + 4);
    uint4 rv = *(const uint4*)(resb + (size_t)gw * 128 + sub * 8);
    float a[8];
    a[0] = acc[0] * dg + b0.x; a[1] = acc[1] * dg + b0.y;
    a[2] = acc[2] * dg + b0.z; a[3] = acc[3] * dg + b0.w;
    a[4] = acc[4] * dg + b1v.x; a[5] = acc[5] * dg + b1v.y;
    a[6] = acc[6] * dg + b1v.z; a[7] = acc[7] * dg + b1v.w;
    add2(a[0], a[1], rv.x); add2(a[2], a[3], rv.y);
    add2(a[4], a[5], rv.z); add2(a[6], a[7], rv.w);
    uint4 o;
    o.x = pack2(a[0], a[1]); o.y = pack2(a[2], a[3]);
    o.z = pack2(a[4], a[5]); o.w = pack2(a[6], a[7]);
    *(uint4*)(hf + (size_t)gw * 128 + sub * 8) = o;
    // result2 (degree head)
    float4 w0 = *(const float4*)(wdeg + sub * 8);
    float4 w1 = *(const float4*)(wdeg + sub * 8 + 4);
    float t = a[0] * w0.x + a[1] * w0.y + a[2] * w0.z + a[3] * w0.w +
              a[4] * w1.x + a[5] * w1.y + a[6] * w1.z + a[7] * w1.w;
#pragma unroll
    for (int mk = 8; mk >= 1; mk >>= 1) t += __shfl_xor(t, mk);
    if (sub == 0) __builtin_nontemporal_store(t + bdeg[0], out2 + gw);
    // log_softmax
    float mx = a[0];
#pragma unroll
    for (int i = 1; i < 8; ++i) mx = fmaxf(mx, a[i]);
#pragma unroll
    for (int mk = 8; mk >= 1; mk >>= 1) mx = fmaxf(mx, __shfl_xor(mx, mk));
    float l = 0.f;
#pragma unroll
    for (int i = 0; i < 8; ++i) l += __expf(a[i] - mx);
#pragma unroll
    for (int mk = 8; mk >= 1; mk >>= 1) l += __shfl_xor(l, mk);
    float ls = mx + __logf(l);
    f32x4 o0 = {a[0] - ls, a[1] - ls, a[2] - ls, a[3] - ls};
    f32x4 o1 = {a[4] - ls, a[5] - ls, a[6] - ls, a[7] - ls};
    __builtin_nontemporal_store(o0, (f32x4*)(out1 + (size_t)gw * 128 + sub * 8));
    __builtin_nontemporal_store(o1, (f32x4*)(out1 + (size_t)gw * 128 + sub * 8 + 4));
  }
}

// ---------------- launch ----------------

extern "C" void kernel_launch(void* const* d_in, const int* in_sizes, int n_in,
                              void* d_out, int out_size, void* d_ws, size_t ws_size,
                              hipStream_t stream) {
  const float* x   = (const float*)d_in[0];
  const int*   ei  = (const int*)d_in[1];
  const float* W1  = (const float*)d_in[2];
  const float* b1  = (const float*)d_in[3];
  const float* W2  = (const float*)d_in[4];
  const float* b2  = (const float*)d_in[5];
  const float* Wd  = (const float*)d_in[6];
  const float* bd  = (const float*)d_in[7];
  const float* Wdg = (const float*)d_in[8];
  const float* bdg = (const float*)d_in[9];
  const float* W3  = (const float*)d_in[10];
  const float* b3  = (const float*)d_in[11];

  const int N = in_sizes[0] / 256;
  const int E = in_sizes[1] / 2;

  // ---- workspace (~35 MB) ----
  char* w = (char*)d_ws;
  auto alloc = [&](size_t bytes) {
    char* p = w;
    w += (bytes + 255) & ~(size_t)255;
    return p;
  };
  unsigned short* W1t  = (unsigned short*)alloc((size_t)256 * 128 * 2);
  unsigned short* Wdt  = (unsigned short*)alloc((size_t)256 * 128 * 2);
  unsigned short* W2t  = (unsigned short*)alloc((size_t)128 * 128 * 2);
  unsigned short* W3t  = (unsigned short*)alloc((size_t)128 * 128 * 2);
  unsigned short* bufC = (unsigned short*)alloc((size_t)N * 128 * 2);  // h1/h bf16; pairs scratch pre-agg1
  int*   deg      = (int*)alloc((size_t)N * 4);
  float* dinv     = (float*)alloc((size_t)(N + 128) * 4);  // padded for GEMM-tail float4 reads
  int*   row_start= (int*)alloc((size_t)(N + 1) * 4);
  int*   cursor   = (int*)alloc((size_t)N * 4);
  int*   partials = (int*)alloc(4096);
  int*   csr_src  = (int*)alloc((size_t)E * 4);
  int*   bcnt     = (int*)alloc(2048);            // 256 bucket counts + ovf_cnt (zeroed in wtrans4)
  int*   ovf_cnt  = bcnt + 256;
  int2*  ovf      = (int2*)alloc((size_t)OVF_CAP * 8);

  // ---- d_out regions; out3 region doubles as bf16 scratch (bufA + resb) ----
  float* out1 = (float*)d_out;               // final log_softmax
  float* out2 = out1 + (size_t)N * 128;
  float* out3 = out2 + (size_t)N;
  unsigned short* bufA = (unsigned short*)out3;        // xW1*dinv / h1W2 bf16 (1st half)
  unsigned short* resb = bufA + (size_t)N * 128;       // residual bf16 (2nd half)

  // pairs intermediate reuses bufC (dead until k_agg1)
  const int nbuck = CDIV(N, 512);                // <=256 for N<=131072
  int cap = (E / nbuck) + (E / nbuck) / 2;       // 1.5x avg bucket size
  cap = (cap + 255) & ~255;
  size_t bufC_bytes = (size_t)N * 128 * 2;
  if ((size_t)nbuck * cap * 8 > bufC_bytes)
    cap = (int)(bufC_bytes / ((size_t)nbuck * 8));
  int2* pairs = (int2*)bufC;

  // wtrans + deg/bcnt zero-init (folded; replaces 2 memsets)
  k_wtrans4<<<CDIV(98304 + N + 512, 256), 256, 0, stream>>>(
      W1, Wd, W2, W3, W1t, Wdt, W2t, W3t, deg, bcnt, N);

  // deg count + pair binning (one ei pass)
  k_binA<<<CDIV(E, BIN_CHUNK), 256, 0, stream>>>(ei, E, nbuck, cap, deg, pairs,
                                                 bcnt, ovf, ovf_cnt);

  // dinv before gemm_x2 (O1 rows scaled by dinv)
  const int nb = CDIV(N, 2048);
  k_scan1<<<nb, 256, 0, stream>>>(deg, row_start, partials, dinv, N);
  k_scan3<<<CDIV(N, 256), 256, 0, stream>>>(partials, row_start, cursor, N, E);

  // fused x@W1*dinv -> bufA (bf16), x@Wd+bd -> resb (bf16 residual)
  k_gemm_x2<<<CDIV(N, 128), 512, 0, stream>>>(x, W1t, Wdt, bd, dinv, bufA, resb, N);

  // bucket-local scatter -> csr_src (LDS cursors when no overflow)
  k_binB<<<nbuck + 8, 256, 0, stream>>>(pairs, bcnt, nbuck, cap, ovf, ovf_cnt,
                                        cursor, csr_src, N);

  // layer 1: aggregate dinv-scaled xW1, *dg, +b1, relu -> h1 (bufC)
  k_agg1<<<CDIV(N, 4), 256, 0, stream>>>(bufA, row_start, csr_src, dinv, b1, bufC, N);

  // h1 @ W2, rows scaled by dinv -> bufA
  k_gemm_h<0><<<CDIV(N, 128), 512, 0, stream>>>(bufC, W2t, nullptr, dinv, bufA, nullptr, N);

  // layer 2 aggregate + b2 + bf16 residual; log_softmax -> out1, deg head -> out2,
  // h bf16 -> bufC
  k_agg2_epi<<<CDIV(N, 4), 256, 0, stream>>>(bufA, row_start, csr_src, dinv,
                                             b2, resb, out1, Wdg, bdg, out2, bufC, N);

  // result3 = h @ W3 + b3 -> out3
  k_gemm_h<1><<<CDIV(N, 128), 512, 0, stream>>>(bufC, W3t, b3, nullptr, nullptr, out3, N);
}

// Round 10
// 441.610 us; speedup vs baseline: 1.8328x; 1.1262x over previous
//
#include <hip/hip_runtime.h>

// GNN_22505628631761: 2-layer GCN (sym-norm, self-loops) + residual + 3 outputs.
// fp32 in/out; bf16 MFMA GEMMs + bf16 h buffers internally.
// R10: GEMMs LDS-staged + counted vmcnt; aggs 4-edges/instr.
// R13: binB LDS-cursors. R14: bf16 residual (-51MB), scan2 folded (497us).
// R15: CSR-build collapsed. deg is derivable per-bucket in binB (LDS histogram
//      of 512 dst values) -> binA's 1.6M global deg atomics REMOVED; scan1 +
//      scan3 folded into k_binBC: row_start = redundant 256-wide bcnt prefix
//      (L2-hot) + local LDS exclusive scan; binBC writes dinv/row_start and
//      scatters csr via LDS cursors. deg/cursor arrays gone. 10 -> 8 dispatches.

typedef __attribute__((ext_vector_type(8))) short bf16x8;
typedef __attribute__((ext_vector_type(4))) float f32x4;

#define CDIV(a, b) (((a) + (b) - 1) / (b))

#define GLOBAL_AS __attribute__((address_space(1)))
#define LDS_AS __attribute__((address_space(3)))

__device__ __forceinline__ void gload16(const void* g, void* l) {
  __builtin_amdgcn_global_load_lds((const GLOBAL_AS unsigned int*)g,
                                   (LDS_AS unsigned int*)l, 16, 0, 0);
}

__device__ __forceinline__ float b2f(unsigned short u) {
  union { unsigned int i; float f; } x; x.i = ((unsigned int)u) << 16; return x.f;
}
__device__ __forceinline__ unsigned short f2b(float f) {
  union { float f; unsigned int i; } x; x.f = f;
  unsigned int r = x.i + 0x7fffu + ((x.i >> 16) & 1u);  // RNE
  return (unsigned short)(r >> 16);
}
// add both bf16 halves of u into a0 (low) / a1 (high)
__device__ __forceinline__ void add2(float& a0, float& a1, unsigned int u) {
  union { unsigned int i; float f; } lo, hi;
  lo.i = u << 16; hi.i = u & 0xffff0000u;
  a0 += lo.f; a1 += hi.f;
}
__device__ __forceinline__ unsigned int pack2(float lo, float hi) {
  return __builtin_amdgcn_perm(__float_as_uint(hi) + 0x8000u,
                               __float_as_uint(lo) + 0x8000u, 0x07060302u);
}

// ---------------- setup kernels ----------------

// all four W [K][N] fp32 -> Wt [N][K] bf16, plus bcnt/ovf_cnt zero tail
__global__ void k_wtrans4(const float* __restrict__ W1, const float* __restrict__ Wd,
                          const float* __restrict__ W2, const float* __restrict__ W3,
                          unsigned short* __restrict__ W1t, unsigned short* __restrict__ Wdt,
                          unsigned short* __restrict__ W2t, unsigned short* __restrict__ W3t,
                          int* __restrict__ bcnt) {
  int idx = blockIdx.x * blockDim.x + threadIdx.x;
  if (idx >= 98304) {
    idx -= 98304;
    if (idx < 512) bcnt[idx] = 0;
    return;
  }
  const float* in; unsigned short* out; int K, N;
  if (idx < 32768)       { in = W1; out = W1t; K = 256; N = 128; }
  else if (idx < 65536)  { in = Wd; out = Wdt; K = 256; N = 128; idx -= 32768; }
  else if (idx < 81920)  { in = W2; out = W2t; K = 128; N = 128; idx -= 65536; }
  else                   { in = W3; out = W3t; K = 128; N = 128; idx -= 81920; }
  int k = idx / N, nn = idx - k * N;
  out[nn * K + k] = f2b(in[idx]);
}

// ---------------- 2-pass radix binning (+ fused deg/scan/CSR) ----------------

#define BIN_CHUNK 4096  // edges per block in pass A (16/thread)
#define OVF_CAP 65536

__global__ __launch_bounds__(256) void k_binA(
    const int* __restrict__ ei, int E, int nbuck, int cap,
    int2* __restrict__ pairs, int* __restrict__ bcnt,
    int2* __restrict__ ovf, int* __restrict__ ovf_cnt) {
  __shared__ int lcnt[256];
  __shared__ int lbase[256];
  int tid = threadIdx.x;
  for (int i = tid; i < nbuck; i += 256) lcnt[i] = 0;
  __syncthreads();
  int base_e = blockIdx.x * BIN_CHUNK;
  int src[16], dst[16], lofs[16];
#pragma unroll
  for (int i = 0; i < 16; ++i) {
    int e = base_e + i * 256 + tid;
    if (e < E) {
      int s = ei[e], d = ei[E + e];
      src[i] = s; dst[i] = d;
      lofs[i] = atomicAdd(&lcnt[d >> 9], 1);
    } else {
      dst[i] = -1;
    }
  }
  __syncthreads();
  for (int b = tid; b < nbuck; b += 256)
    lbase[b] = atomicAdd(&bcnt[b], lcnt[b]);
  __syncthreads();
#pragma unroll
  for (int i = 0; i < 16; ++i) {
    if (dst[i] < 0) continue;
    int b = dst[i] >> 9;
    int gpos = lbase[b] + lofs[i];
    if (gpos < cap) {
      pairs[(size_t)b * cap + gpos] = make_int2(src[i], dst[i]);
    } else {
      int op = atomicAdd(ovf_cnt, 1);
      if (op < OVF_CAP) ovf[op] = make_int2(src[i], dst[i]);
    }
  }
}

// Per-bucket: histogram deg (incl. overflow edges), write dinv + row_start
// (global base = redundant prefix over bcnt), scatter csr via LDS cursors.
__global__ __launch_bounds__(256) void k_binBC(
    const int2* __restrict__ pairs, const int* __restrict__ bcnt,
    int nbuck, int cap,
    const int2* __restrict__ ovf, const int* __restrict__ ovf_cnt,
    float* __restrict__ dinv, int* __restrict__ row_start,
    int* __restrict__ csr_src, int n, int E) {
  __shared__ int hist[512];
  __shared__ int sb[256];
  const int b = blockIdx.x;
  const int tid = threadIdx.x;
  const int nbase = b << 9;
  hist[tid] = 0; hist[tid + 256] = 0;
  __syncthreads();
  int total = bcnt[b];
  int cnt = (total < cap) ? total : cap;
  const int2* p = pairs + (size_t)b * cap;
  for (int i = tid; i < cnt; i += 256)
    atomicAdd(&hist[p[i].y - nbase], 1);
  int ov = *ovf_cnt; if (ov > OVF_CAP) ov = OVF_CAP;
  if (ov > 0) {
    for (int i = tid; i < ov; i += 256) {
      int2 e = ovf[i];
      if ((e.y >> 9) == b) atomicAdd(&hist[e.y - nbase], 1);
    }
  }
  __syncthreads();
  int h0 = hist[2 * tid], h1 = hist[2 * tid + 1];
  // global base: inclusive scan of bcnt (<=256 buckets), redundant per block
  sb[tid] = (tid < nbuck) ? bcnt[tid] : 0;
  __syncthreads();
  for (int off = 1; off < 256; off <<= 1) {
    int t = (tid >= off) ? sb[tid - off] : 0;
    __syncthreads();
    sb[tid] += t;
    __syncthreads();
  }
  int gbase = (b > 0) ? sb[b - 1] : 0;
  __syncthreads();
  // local exclusive scan over 512 (pairs per thread)
  sb[tid] = h0 + h1;
  __syncthreads();
  for (int off = 1; off < 256; off <<= 1) {
    int t = (tid >= off) ? sb[tid - off] : 0;
    __syncthreads();
    sb[tid] += t;
    __syncthreads();
  }
  int exc = (tid > 0) ? sb[tid - 1] : 0;
  int c0 = gbase + exc, c1 = gbase + exc + h0;
  int node0 = nbase + 2 * tid, node1 = node0 + 1;
  if (node0 < n) {
    dinv[node0] = 1.0f / sqrtf((float)h0 + 1.0f);
    row_start[node0] = c0;
  }
  if (node1 < n) {
    dinv[node1] = 1.0f / sqrtf((float)h1 + 1.0f);
    row_start[node1] = c1;
  }
  if (b == 0 && tid == 0) row_start[n] = E;
  __syncthreads();
  hist[2 * tid] = c0; hist[2 * tid + 1] = c1;   // become cursors
  __syncthreads();
  for (int i = tid; i < cnt; i += 256) {
    int2 e = p[i];
    int pos = atomicAdd(&hist[e.y - nbase], 1);
    csr_src[pos] = e.x;
  }
  if (ov > 0) {
    for (int i = tid; i < ov; i += 256) {
      int2 e = ovf[i];
      if ((e.y >> 9) == b) {
        int pos = atomicAdd(&hist[e.y - nbase], 1);
        csr_src[pos] = e.x;
      }
    }
  }
}

// ---------------- GEMMs (MFMA bf16 16x16x32, LDS-staged) ----------------
// Block 128 rows x 128 cols, 512 thr (8 waves, 4x2), wave tile 32x64 (2x4).
// LDS dest linear (global_load_lds), source pre-swizzled slot^=(row&7).
// C/D: col=lane&15, row=(lane>>4)*4+reg.

__global__ __launch_bounds__(512) void k_gemm_x2(
    const float* __restrict__ X,             // [n,256] fp32
    const unsigned short* __restrict__ B1t,  // [128,256] bf16 = W1^T
    const unsigned short* __restrict__ B2t,  // [128,256] bf16 = Wd^T
    const float* __restrict__ bias2,         // bd
    const float* __restrict__ dinvp,         // [n+pad] row scale for O1
    unsigned short* __restrict__ O1,         // xW1*dinv bf16 [n,128]
    unsigned short* __restrict__ O2,         // residual bf16 [n,128]
    int n) {
  __shared__ char lds[65536];  // 2 x (A 16KB + B 16KB)
  const int flat = threadIdx.x;
  const int wave = flat >> 6, lane = flat & 63;
  const int l15 = lane & 15, q = lane >> 4;
  const int wM = wave >> 1, wN = wave & 1;
  const int rowBase = blockIdx.x * 128;
  const int colBase = wN * 64;

  auto stage = [&](int kb, int buf) {
    char* ldsA = lds + buf * 32768;
    char* ldsB = ldsA + 16384;
    const char* Xb = (const char*)X;
#pragma unroll
    for (int j = 0; j < 2; ++j) {
      int i = j * 512 + flat;
      int row = i >> 3, pslot = i & 7;
      int lslot = pslot ^ (row & 7);
      int rowc = rowBase + row; if (rowc >= n) rowc = n - 1;
      gload16(Xb + (size_t)rowc * 1024 + (size_t)(kb * 128 + lslot * 16),
              ldsA + (j * 512 + wave * 64) * 16);
    }
#pragma unroll
    for (int j = 0; j < 2; ++j) {
      int i = j * 512 + flat;
      int col = i >> 3, pslot = i & 7;
      int lslot = pslot ^ (col & 7);
      const char* src = (lslot >= 4) ? (const char*)B2t : (const char*)B1t;
      gload16(src + (size_t)col * 512 + kb * 64 + (lslot & 3) * 16,
              ldsB + (j * 512 + wave * 64) * 16);
    }
  };

  f32x4 acc1[2][4], acc2[2][4];
#pragma unroll
  for (int i = 0; i < 2; ++i)
#pragma unroll
    for (int j = 0; j < 4; ++j) {
      acc1[i][j] = (f32x4){0.f, 0.f, 0.f, 0.f};
      acc2[i][j] = (f32x4){0.f, 0.f, 0.f, 0.f};
    }

  stage(0, 0);
  stage(1, 1);

#pragma unroll
  for (int kb = 0; kb < 8; ++kb) {
    int cur = kb & 1;
    if (kb < 7) asm volatile("s_waitcnt vmcnt(4)" ::: "memory");
    else        asm volatile("s_waitcnt vmcnt(0)" ::: "memory");
    __builtin_amdgcn_s_barrier();
    char* ldsA = lds + cur * 32768;
    char* ldsB = ldsA + 16384;
    bf16x8 a[2], b1v[4], b2v[4];
#pragma unroll
    for (int mt = 0; mt < 2; ++mt) {
      int row = wM * 32 + mt * 16 + l15;
      uint4 lo = *(const uint4*)(ldsA + row * 128 + (((2 * q) ^ (row & 7)) * 16));
      uint4 hi = *(const uint4*)(ldsA + row * 128 + (((2 * q + 1) ^ (row & 7)) * 16));
      union { bf16x8 v; unsigned int u[4]; } r;
      r.u[0] = __builtin_amdgcn_perm(lo.y + 0x8000u, lo.x + 0x8000u, 0x07060302u);
      r.u[1] = __builtin_amdgcn_perm(lo.w + 0x8000u, lo.z + 0x8000u, 0x07060302u);
      r.u[2] = __builtin_amdgcn_perm(hi.y + 0x8000u, hi.x + 0x8000u, 0x07060302u);
      r.u[3] = __builtin_amdgcn_perm(hi.w + 0x8000u, hi.z + 0x8000u, 0x07060302u);
      a[mt] = r.v;
    }
#pragma unroll
    for (int nt = 0; nt < 4; ++nt) {
      int col = colBase + nt * 16 + l15;
      b1v[nt] = *(const bf16x8*)(ldsB + col * 128 + ((q ^ (col & 7)) * 16));
      b2v[nt] = *(const bf16x8*)(ldsB + col * 128 + (((4 + q) ^ (col & 7)) * 16));
    }
#pragma unroll
    for (int mt = 0; mt < 2; ++mt)
#pragma unroll
      for (int nt = 0; nt < 4; ++nt) {
        acc1[mt][nt] = __builtin_amdgcn_mfma_f32_16x16x32_bf16(a[mt], b1v[nt], acc1[mt][nt], 0, 0, 0);
        acc2[mt][nt] = __builtin_amdgcn_mfma_f32_16x16x32_bf16(a[mt], b2v[nt], acc2[mt][nt], 0, 0, 0);
      }
    asm volatile("s_waitcnt lgkmcnt(0)" ::: "memory");
    __builtin_amdgcn_s_barrier();
    if (kb < 6) stage(kb + 2, cur);
  }

#pragma unroll
  for (int mt = 0; mt < 2; ++mt) {
    float4 dv = *(const float4*)(dinvp + rowBase + wM * 32 + mt * 16 + q * 4);
#pragma unroll
    for (int nt = 0; nt < 4; ++nt) {
      int col = colBase + nt * 16 + l15;
      float bb = bias2[col];
#pragma unroll
      for (int r = 0; r < 4; ++r) {
        int row = rowBase + wM * 32 + mt * 16 + q * 4 + r;
        if (row < n) {
          float dvr = (r == 0) ? dv.x : (r == 1) ? dv.y : (r == 2) ? dv.z : dv.w;
          O1[(size_t)row * 128 + col] = f2b(acc1[mt][nt][r] * dvr);
          O2[(size_t)row * 128 + col] = f2b(acc2[mt][nt][r] + bb);
        }
      }
    }
  }
}

// A bf16 [n,128] @ Bt bf16 [128,128] -> bf16*dinv (OUT_F32=0) or fp32+bias (=1).
template <int OUT_F32>
__global__ __launch_bounds__(512) void k_gemm_h(
    const unsigned short* __restrict__ X, const unsigned short* __restrict__ Bt,
    const float* __restrict__ bias, const float* __restrict__ dinvp,
    unsigned short* __restrict__ Ob, float* __restrict__ Of, int n) {
  __shared__ char lds[65536];
  const int flat = threadIdx.x;
  const int wave = flat >> 6, lane = flat & 63;
  const int l15 = lane & 15, q = lane >> 4;
  const int wM = wave >> 1, wN = wave & 1;
  const int rowBase = blockIdx.x * 128;
  const int colBase = wN * 64;

  auto stage = [&](int ks, int buf) {
    char* ldsA = lds + buf * 32768;
    char* ldsB = ldsA + 16384;
#pragma unroll
    for (int j = 0; j < 2; ++j) {
      int i = j * 512 + flat;
      int row = i >> 3, pslot = i & 7;
      int lslot = pslot ^ (row & 7);
      int rowc = rowBase + row; if (rowc >= n) rowc = n - 1;
      gload16((const char*)X + (size_t)rowc * 256 + ks * 128 + lslot * 16,
              ldsA + (j * 512 + wave * 64) * 16);
    }
#pragma unroll
    for (int j = 0; j < 2; ++j) {
      int i = j * 512 + flat;
      int col = i >> 3, pslot = i & 7;
      int lslot = pslot ^ (col & 7);
      gload16((const char*)Bt + (size_t)col * 256 + ks * 128 + lslot * 16,
              ldsB + (j * 512 + wave * 64) * 16);
    }
  };

  f32x4 acc[2][4];
#pragma unroll
  for (int i = 0; i < 2; ++i)
#pragma unroll
    for (int j = 0; j < 4; ++j) acc[i][j] = (f32x4){0.f, 0.f, 0.f, 0.f};

  stage(0, 0);
  stage(1, 1);

#pragma unroll
  for (int ks = 0; ks < 2; ++ks) {
    if (ks == 0) asm volatile("s_waitcnt vmcnt(4)" ::: "memory");
    else         asm volatile("s_waitcnt vmcnt(0)" ::: "memory");
    __builtin_amdgcn_s_barrier();
    char* ldsA = lds + ks * 32768;
    char* ldsB = ldsA + 16384;
#pragma unroll
    for (int k2 = 0; k2 < 2; ++k2) {
      bf16x8 a[2], b[4];
#pragma unroll
      for (int mt = 0; mt < 2; ++mt) {
        int row = wM * 32 + mt * 16 + l15;
        a[mt] = *(const bf16x8*)(ldsA + row * 128 + (((k2 * 4 + q) ^ (row & 7)) * 16));
      }
#pragma unroll
      for (int nt = 0; nt < 4; ++nt) {
        int col = colBase + nt * 16 + l15;
        b[nt] = *(const bf16x8*)(ldsB + col * 128 + (((k2 * 4 + q) ^ (col & 7)) * 16));
      }
#pragma unroll
      for (int mt = 0; mt < 2; ++mt)
#pragma unroll
        for (int nt = 0; nt < 4; ++nt)
          acc[mt][nt] = __builtin_amdgcn_mfma_f32_16x16x32_bf16(a[mt], b[nt], acc[mt][nt], 0, 0, 0);
    }
  }

#pragma unroll
  for (int mt = 0; mt < 2; ++mt) {
    float4 dv;
    if (!OUT_F32) dv = *(const float4*)(dinvp + rowBase + wM * 32 + mt * 16 + q * 4);
#pragma unroll
    for (int nt = 0; nt < 4; ++nt) {
      int col = colBase + nt * 16 + l15;
      float bb = OUT_F32 ? bias[col] : 0.f;
#pragma unroll
      for (int r = 0; r < 4; ++r) {
        int row = rowBase + wM * 32 + mt * 16 + q * 4 + r;
        if (row < n) {
          if (OUT_F32) {
            __builtin_nontemporal_store(acc[mt][nt][r] + bb, &Of[(size_t)row * 128 + col]);
          } else {
            float dvr = (r == 0) ? dv.x : (r == 1) ? dv.y : (r == 2) ? dv.z : dv.w;
            Ob[(size_t)row * 128 + col] = f2b(acc[mt][nt][r] * dvr);
          }
        }
      }
    }
  }
}

// ---------------- aggregation (wave per node, 4 edges/instr) ----------------
// grp = lane>>4 handles edge (j+grp); sub = lane&15 holds feats [sub*8, sub*8+8).
// h rows are pre-scaled by dinv[src]; coef = dg applied once at the end.

__device__ __forceinline__ void agg_edges4(
    const unsigned short* __restrict__ h, const int* __restrict__ csr_src,
    int beg, int end, int lane, int grp, int sub, float* acc) {
  for (int base = beg; base < end; base += 64) {
    int m = end - base; if (m > 64) m = 64;
    int idx_l = (base + lane < end) ? csr_src[base + lane] : 0;
    for (int j = 0; j < m; j += 16) {
      int s0 = __builtin_amdgcn_ds_bpermute((j + grp) << 2, idx_l);
      int s1 = __builtin_amdgcn_ds_bpermute((j + 4 + grp) << 2, idx_l);
      int s2 = __builtin_amdgcn_ds_bpermute((j + 8 + grp) << 2, idx_l);
      int s3 = __builtin_amdgcn_ds_bpermute((j + 12 + grp) << 2, idx_l);
      uint4 v0 = *(const uint4*)(h + (size_t)s0 * 128 + sub * 8);
      uint4 v1 = *(const uint4*)(h + (size_t)s1 * 128 + sub * 8);
      uint4 v2 = *(const uint4*)(h + (size_t)s2 * 128 + sub * 8);
      uint4 v3 = *(const uint4*)(h + (size_t)s3 * 128 + sub * 8);
      if (j + grp < m) {
        add2(acc[0], acc[1], v0.x); add2(acc[2], acc[3], v0.y);
        add2(acc[4], acc[5], v0.z); add2(acc[6], acc[7], v0.w);
      }
      if (j + 4 + grp < m) {
        add2(acc[0], acc[1], v1.x); add2(acc[2], acc[3], v1.y);
        add2(acc[4], acc[5], v1.z); add2(acc[6], acc[7], v1.w);
      }
      if (j + 8 + grp < m) {
        add2(acc[0], acc[1], v2.x); add2(acc[2], acc[3], v2.y);
        add2(acc[4], acc[5], v2.z); add2(acc[6], acc[7], v2.w);
      }
      if (j + 12 + grp < m) {
        add2(acc[0], acc[1], v3.x); add2(acc[2], acc[3], v3.y);
        add2(acc[4], acc[5], v3.z); add2(acc[6], acc[7], v3.w);
      }
    }
  }
}

__device__ __forceinline__ void grp_reduce(float* acc) {
#pragma unroll
  for (int i = 0; i < 8; ++i) {
    acc[i] += __shfl_xor(acc[i], 16);
    acc[i] += __shfl_xor(acc[i], 32);
  }
}

__global__ __launch_bounds__(256) void k_agg1(
    const unsigned short* __restrict__ h,   // dinv-scaled xW1 bf16 [n,128]
    const int* __restrict__ row_start, const int* __restrict__ csr_src,
    const float* __restrict__ dinv,
    const float* __restrict__ bias,         // b1
    unsigned short* __restrict__ hout, int n) {
  int gw = blockIdx.x * 4 + (threadIdx.x >> 6);
  int lane = threadIdx.x & 63;
  int grp = lane >> 4, sub = lane & 15;
  if (gw >= n) return;
  int beg = row_start[gw], end = row_start[gw + 1];
  float acc[8] = {0.f, 0.f, 0.f, 0.f, 0.f, 0.f, 0.f, 0.f};
  agg_edges4(h, csr_src, beg, end, lane, grp, sub, acc);
  grp_reduce(acc);
  if (grp == 0) {
    float dg = dinv[gw];
    uint4 sv = *(const uint4*)(h + (size_t)gw * 128 + sub * 8);  // self (pre-scaled)
    add2(acc[0], acc[1], sv.x); add2(acc[2], acc[3], sv.y);
    add2(acc[4], acc[5], sv.z); add2(acc[6], acc[7], sv.w);
    float4 b0 = *(const float4*)(bias + sub * 8);
    float4 b1v = *(const float4*)(bias + sub * 8 + 4);
    float a[8];
    a[0] = fmaxf(acc[0] * dg + b0.x, 0.f); a[1] = fmaxf(acc[1] * dg + b0.y, 0.f);
    a[2] = fmaxf(acc[2] * dg + b0.z, 0.f); a[3] = fmaxf(acc[3] * dg + b0.w, 0.f);
    a[4] = fmaxf(acc[4] * dg + b1v.x, 0.f); a[5] = fmaxf(acc[5] * dg + b1v.y, 0.f);
    a[6] = fmaxf(acc[6] * dg + b1v.z, 0.f); a[7] = fmaxf(acc[7] * dg + b1v.w, 0.f);
    uint4 o;
    o.x = pack2(a[0], a[1]); o.y = pack2(a[2], a[3]);
    o.z = pack2(a[4], a[5]); o.w = pack2(a[6], a[7]);
    *(uint4*)(hout + (size_t)gw * 128 + sub * 8) = o;
  }
}

__global__ __launch_bounds__(256) void k_agg2_epi(
    const unsigned short* __restrict__ h,   // dinv-scaled h1@W2 bf16 [n,128]
    const int* __restrict__ row_start, const int* __restrict__ csr_src,
    const float* __restrict__ dinv,
    const float* __restrict__ bias,    // b2
    const unsigned short* __restrict__ resb,  // residual bf16 [n,128]
    float* __restrict__ out1,          // log_softmax out
    const float* __restrict__ wdeg, const float* __restrict__ bdeg,
    float* __restrict__ out2,          // [n]
    unsigned short* __restrict__ hf,   // h bf16 [n,128]
    int n) {
  int gw = blockIdx.x * 4 + (threadIdx.x >> 6);
  int lane = threadIdx.x & 63;
  int grp = lane >> 4, sub = lane & 15;
  if (gw >= n) return;
  int beg = row_start[gw], end = row_start[gw + 1];
  float acc[8] = {0.f, 0.f, 0.f, 0.f, 0.f, 0.f, 0.f, 0.f};
  agg_edges4(h, csr_src, beg, end, lane, grp, sub, acc);
  grp_reduce(acc);
  if (grp == 0) {
    float dg = dinv[gw];
    uint4 sv = *(const uint4*)(h + (size_t)gw * 128 + sub * 8);
    add2(acc[0], acc[1], sv.x); add2(acc[2], acc[3], sv.y);
    add2(acc[4], acc[5], sv.z); add2(acc[6], acc[7], sv.w);
    float4 b0 = *(const float4*)(bias + sub * 8);
    float4 b1v = *(const float4*)(bias + sub * 8 + 4);
    uint4 rv = *(const uint4*)(resb + (size_t)gw * 128 + sub * 8);
    float a[8];
    a[0] = acc[0] * dg + b0.x; a[1] = acc[1] * dg + b0.y;
    a[2] = acc[2] * dg + b0.z; a[3] = acc[3] * dg + b0.w;
    a[4] = acc[4] * dg + b1v.x; a[5] = acc[5] * dg + b1v.y;
    a[6] = acc[6] * dg + b1v.z; a[7] = acc[7] * dg + b1v.w;
    add2(a[0], a[1], rv.x); add2(a[2], a[3], rv.y);
    add2(a[4], a[5], rv.z); add2(a[6], a[7], rv.w);
    uint4 o;
    o.x = pack2(a[0], a[1]); o.y = pack2(a[2], a[3]);
    o.z = pack2(a[4], a[5]); o.w = pack2(a[6], a[7]);
    *(uint4*)(hf + (size_t)gw * 128 + sub * 8) = o;
    // result2 (degree head)
    float4 w0 = *(const float4*)(wdeg + sub * 8);
    float4 w1 = *(const float4*)(wdeg + sub * 8 + 4);
    float t = a[0] * w0.x + a[1] * w0.y + a[2] * w0.z + a[3] * w0.w +
              a[4] * w1.x + a[5] * w1.y + a[6] * w1.z + a[7] * w1.w;
#pragma unroll
    for (int mk = 8; mk >= 1; mk >>= 1) t += __shfl_xor(t, mk);
    if (sub == 0) __builtin_nontemporal_store(t + bdeg[0], out2 + gw);
    // log_softmax
    float mx = a[0];
#pragma unroll
    for (int i = 1; i < 8; ++i) mx = fmaxf(mx, a[i]);
#pragma unroll
    for (int mk = 8; mk >= 1; mk >>= 1) mx = fmaxf(mx, __shfl_xor(mx, mk));
    float l = 0.f;
#pragma unroll
    for (int i = 0; i < 8; ++i) l += __expf(a[i] - mx);
#pragma unroll
    for (int mk = 8; mk >= 1; mk >>= 1) l += __shfl_xor(l, mk);
    float ls = mx + __logf(l);
    f32x4 o0 = {a[0] - ls, a[1] - ls, a[2] - ls, a[3] - ls};
    f32x4 o1 = {a[4] - ls, a[5] - ls, a[6] - ls, a[7] - ls};
    __builtin_nontemporal_store(o0, (f32x4*)(out1 + (size_t)gw * 128 + sub * 8));
    __builtin_nontemporal_store(o1, (f32x4*)(out1 + (size_t)gw * 128 + sub * 8 + 4));
  }
}

// ---------------- launch ----------------

extern "C" void kernel_launch(void* const* d_in, const int* in_sizes, int n_in,
                              void* d_out, int out_size, void* d_ws, size_t ws_size,
                              hipStream_t stream) {
  const float* x   = (const float*)d_in[0];
  const int*   ei  = (const int*)d_in[1];
  const float* W1  = (const float*)d_in[2];
  const float* b1  = (const float*)d_in[3];
  const float* W2  = (const float*)d_in[4];
  const float* b2  = (const float*)d_in[5];
  const float* Wd  = (const float*)d_in[6];
  const float* bd  = (const float*)d_in[7];
  const float* Wdg = (const float*)d_in[8];
  const float* bdg = (const float*)d_in[9];
  const float* W3  = (const float*)d_in[10];
  const float* b3  = (const float*)d_in[11];

  const int N = in_sizes[0] / 256;
  const int E = in_sizes[1] / 2;

  // ---- workspace (~34 MB) ----
  char* w = (char*)d_ws;
  auto alloc = [&](size_t bytes) {
    char* p = w;
    w += (bytes + 255) & ~(size_t)255;
    return p;
  };
  unsigned short* W1t  = (unsigned short*)alloc((size_t)256 * 128 * 2);
  unsigned short* Wdt  = (unsigned short*)alloc((size_t)256 * 128 * 2);
  unsigned short* W2t  = (unsigned short*)alloc((size_t)128 * 128 * 2);
  unsigned short* W3t  = (unsigned short*)alloc((size_t)128 * 128 * 2);
  unsigned short* bufC = (unsigned short*)alloc((size_t)N * 128 * 2);  // h1/h bf16; pairs scratch pre-agg1
  float* dinv     = (float*)alloc((size_t)(N + 128) * 4);  // padded for GEMM-tail float4 reads
  int*   row_start= (int*)alloc((size_t)(N + 1) * 4);
  int*   csr_src  = (int*)alloc((size_t)E * 4);
  int*   bcnt     = (int*)alloc(2048);            // 256 bucket counts + ovf_cnt (zeroed in wtrans4)
  int*   ovf_cnt  = bcnt + 256;
  int2*  ovf      = (int2*)alloc((size_t)OVF_CAP * 8);

  // ---- d_out regions; out3 region doubles as bf16 scratch (bufA + resb) ----
  float* out1 = (float*)d_out;               // final log_softmax
  float* out2 = out1 + (size_t)N * 128;
  float* out3 = out2 + (size_t)N;
  unsigned short* bufA = (unsigned short*)out3;        // xW1*dinv / h1W2 bf16 (1st half)
  unsigned short* resb = bufA + (size_t)N * 128;       // residual bf16 (2nd half)

  // pairs intermediate reuses bufC (dead until k_agg1)
  const int nbuck = CDIV(N, 512);                // <=256 for N<=131072
  int cap = (E / nbuck) + (E / nbuck) / 2;       // 1.5x avg bucket size
  cap = (cap + 255) & ~255;
  size_t bufC_bytes = (size_t)N * 128 * 2;
  if ((size_t)nbuck * cap * 8 > bufC_bytes)
    cap = (int)(bufC_bytes / ((size_t)nbuck * 8));
  int2* pairs = (int2*)bufC;

  // wtrans + bcnt/ovf_cnt zero-init
  k_wtrans4<<<CDIV(98304 + 512, 256), 256, 0, stream>>>(
      W1, Wd, W2, W3, W1t, Wdt, W2t, W3t, bcnt);

  // pair binning (one ei pass, no deg atomics)
  k_binA<<<CDIV(E, BIN_CHUNK), 256, 0, stream>>>(ei, E, nbuck, cap, pairs,
                                                 bcnt, ovf, ovf_cnt);

  // per-bucket: deg histogram -> dinv/row_start; scatter csr (LDS cursors)
  k_binBC<<<nbuck, 256, 0, stream>>>(pairs, bcnt, nbuck, cap, ovf, ovf_cnt,
                                     dinv, row_start, csr_src, N, E);

  // fused x@W1*dinv -> bufA (bf16), x@Wd+bd -> resb (bf16 residual)
  k_gemm_x2<<<CDIV(N, 128), 512, 0, stream>>>(x, W1t, Wdt, bd, dinv, bufA, resb, N);

  // layer 1: aggregate dinv-scaled xW1, *dg, +b1, relu -> h1 (bufC)
  k_agg1<<<CDIV(N, 4), 256, 0, stream>>>(bufA, row_start, csr_src, dinv, b1, bufC, N);

  // h1 @ W2, rows scaled by dinv -> bufA
  k_gemm_h<0><<<CDIV(N, 128), 512, 0, stream>>>(bufC, W2t, nullptr, dinv, bufA, nullptr, N);

  // layer 2 aggregate + b2 + bf16 residual; log_softmax -> out1, deg head -> out2,
  // h bf16 -> bufC
  k_agg2_epi<<<CDIV(N, 4), 256, 0, stream>>>(bufA, row_start, csr_src, dinv,
                                             b2, resb, out1, Wdg, bdg, out2, bufC, N);

  // result3 = h @ W3 + b3 -> out3
  k_gemm_h<1><<<CDIV(N, 128), 512, 0, stream>>>(bufC, W3t, b3, nullptr, nullptr, out3, N);
}